// Round 1
// baseline (1218.784 us; speedup 1.0000x reference)
//
#include <hip/hip_runtime.h>
#include <cmath>

constexpr int cB = 4, cN = 256, cD = 240, cH = 8, cFF = 1024, cL = 4;
constexpr int cHD = 30, cS = 1030, cPAST = 515, cBS = cB * cS; // 4120
constexpr float EPSF = 1e-5f;

// ---------------- embed: build src (BS x D) from 10 pieces ----------------
__global__ __launch_bounds__(256) void embed_kernel(
    const float* __restrict__ hand_t, const float* __restrict__ head_t,
    const float* __restrict__ hand_m1, const float* __restrict__ head_m1,
    const float* __restrict__ state_t, const float* __restrict__ state_m1,
    const float* __restrict__ hand_pose_m1, const float* __restrict__ head_pose_m1,
    const float* __restrict__ hand_pose_t, const float* __restrict__ head_pose_t,
    float* __restrict__ src)
{
    int idx = blockIdx.x * 256 + threadIdx.x;
    if (idx >= cBS * cD) return;
    int d = idx % cD;
    int r = idx / cD;
    int b = r / cS, s = r % cS;
    const float* p; int off;
    if (s == 0)                  { p = state_m1;     off = b * cD + d; }
    else if (s == 1)             { p = hand_pose_m1; off = b * cD + d; }
    else if (s == 2)             { p = head_pose_m1; off = b * cD + d; }
    else if (s < 3 + cN)         { p = hand_m1;      off = (b * cN + (s - 3)) * cD + d; }
    else if (s < 3 + 2 * cN)     { p = head_m1;      off = (b * cN + (s - 3 - cN)) * cD + d; }
    else if (s == cPAST)         { p = state_t;      off = b * cD + d; }
    else if (s == cPAST + 1)     { p = hand_pose_t;  off = b * cD + d; }
    else if (s == cPAST + 2)     { p = head_pose_t;  off = b * cD + d; }
    else if (s < cPAST + 3 + cN) { p = hand_t;       off = (b * cN + (s - cPAST - 3)) * cD + d; }
    else                         { p = head_t;       off = (b * cN + (s - cPAST - 3 - cN)) * cD + d; }
    src[idx] = p[off];
}

// ---------------- coords: build cs (BS x 3) ----------------
__global__ __launch_bounds__(256) void coords_kernel(
    const float* __restrict__ ch_t, const float* __restrict__ cd_t,
    const float* __restrict__ ch_m1, const float* __restrict__ cd_m1,
    float* __restrict__ cs)
{
    int r = blockIdx.x * 256 + threadIdx.x;
    if (r >= cBS) return;
    int b = r / cS, s = r % cS;
    float x = 0.f, y = 0.f, z = 0.f;
    const float* p = nullptr; int i = 0;
    if (s >= 3 && s < 3 + cN)                       { p = ch_m1; i = s - 3; }
    else if (s >= 3 + cN && s < 3 + 2 * cN)         { p = cd_m1; i = s - 3 - cN; }
    else if (s >= cPAST + 3 && s < cPAST + 3 + cN)  { p = ch_t;  i = s - cPAST - 3; }
    else if (s >= cPAST + 3 + cN)                   { p = cd_t;  i = s - cPAST - 3 - cN; }
    if (p) { x = p[(b * cN + i) * 3 + 0]; y = p[(b * cN + i) * 3 + 1]; z = p[(b * cN + i) * 3 + 2]; }
    cs[r * 3 + 0] = x; cs[r * 3 + 1] = y; cs[r * 3 + 2] = z;
}

// ---------------- generic tiled GEMM: C = A(MxK) @ W^T (W is NxK) + bias ----------------
// EPI: 0 = +bias ; 1 = +bias+residual ; 2 = gelu(+bias)
template<int EPI>
__global__ __launch_bounds__(256) void gemm_bt(
    const float* __restrict__ A, const float* __restrict__ W,
    const float* __restrict__ bias, const float* __restrict__ Rs,
    float* __restrict__ C, int M, int N, int K)
{
    __shared__ float As[16][68];
    __shared__ float Ws[16][68];
    const int tid = threadIdx.x;
    const int tx = tid & 15, ty = tid >> 4;
    const int rowBase = blockIdx.y * 64;
    const int colBase = blockIdx.x * 64;
    const int lr = tid >> 2;          // 0..63
    const int lk = (tid & 3) << 2;    // 0,4,8,12
    const int gr = rowBase + lr;
    const int gc = colBase + lr;
    float acc[4][4] = {};
    for (int kk = 0; kk < K; kk += 16) {
        float4 a4 = make_float4(0.f, 0.f, 0.f, 0.f);
        float4 w4 = make_float4(0.f, 0.f, 0.f, 0.f);
        if (gr < M) a4 = *reinterpret_cast<const float4*>(A + (size_t)gr * K + kk + lk);
        if (gc < N) w4 = *reinterpret_cast<const float4*>(W + (size_t)gc * K + kk + lk);
        __syncthreads();
        As[lk + 0][lr] = a4.x; As[lk + 1][lr] = a4.y; As[lk + 2][lr] = a4.z; As[lk + 3][lr] = a4.w;
        Ws[lk + 0][lr] = w4.x; Ws[lk + 1][lr] = w4.y; Ws[lk + 2][lr] = w4.z; Ws[lk + 3][lr] = w4.w;
        __syncthreads();
#pragma unroll
        for (int k2 = 0; k2 < 16; ++k2) {
            float4 av = *reinterpret_cast<const float4*>(&As[k2][ty << 2]);
            float4 wv = *reinterpret_cast<const float4*>(&Ws[k2][tx << 2]);
            float aa[4] = {av.x, av.y, av.z, av.w};
            float wb[4] = {wv.x, wv.y, wv.z, wv.w};
#pragma unroll
            for (int i = 0; i < 4; ++i)
#pragma unroll
                for (int j = 0; j < 4; ++j)
                    acc[i][j] = fmaf(aa[i], wb[j], acc[i][j]);
        }
    }
#pragma unroll
    for (int i = 0; i < 4; ++i) {
        int row = rowBase + (ty << 2) + i;
        if (row >= M) continue;
#pragma unroll
        for (int j = 0; j < 4; ++j) {
            int col = colBase + (tx << 2) + j;
            if (col >= N) continue;
            float v = acc[i][j] + bias[col];
            if (EPI == 1) v += Rs[(size_t)row * N + col];
            if (EPI == 2) v = 0.5f * v * (1.0f + erff(v * 0.70710678118654752f));
            C[(size_t)row * N + col] = v;
        }
    }
}

// ---------------- QKV GEMM with head scatter: out layout (B,H,S,HD) ----------------
__global__ __launch_bounds__(256) void gemm_qkv(
    const float* __restrict__ A,
    const float* __restrict__ Wq, const float* __restrict__ Wk, const float* __restrict__ Wv,
    const float* __restrict__ bq, const float* __restrict__ bk, const float* __restrict__ bv,
    float* __restrict__ qo, float* __restrict__ ko, float* __restrict__ vo)
{
    const float* W; const float* bias; float* Out;
    if (blockIdx.z == 0)      { W = Wq; bias = bq; Out = qo; }
    else if (blockIdx.z == 1) { W = Wk; bias = bk; Out = ko; }
    else                      { W = Wv; bias = bv; Out = vo; }
    __shared__ float As[16][68];
    __shared__ float Ws[16][68];
    const int tid = threadIdx.x;
    const int tx = tid & 15, ty = tid >> 4;
    const int rowBase = blockIdx.y * 64;
    const int colBase = blockIdx.x * 64;
    const int lr = tid >> 2;
    const int lk = (tid & 3) << 2;
    const int gr = rowBase + lr;
    const int gc = colBase + lr;
    float acc[4][4] = {};
    for (int kk = 0; kk < cD; kk += 16) {
        float4 a4 = make_float4(0.f, 0.f, 0.f, 0.f);
        float4 w4 = make_float4(0.f, 0.f, 0.f, 0.f);
        if (gr < cBS) a4 = *reinterpret_cast<const float4*>(A + (size_t)gr * cD + kk + lk);
        if (gc < cD)  w4 = *reinterpret_cast<const float4*>(W + (size_t)gc * cD + kk + lk);
        __syncthreads();
        As[lk + 0][lr] = a4.x; As[lk + 1][lr] = a4.y; As[lk + 2][lr] = a4.z; As[lk + 3][lr] = a4.w;
        Ws[lk + 0][lr] = w4.x; Ws[lk + 1][lr] = w4.y; Ws[lk + 2][lr] = w4.z; Ws[lk + 3][lr] = w4.w;
        __syncthreads();
#pragma unroll
        for (int k2 = 0; k2 < 16; ++k2) {
            float4 av = *reinterpret_cast<const float4*>(&As[k2][ty << 2]);
            float4 wv = *reinterpret_cast<const float4*>(&Ws[k2][tx << 2]);
            float aa[4] = {av.x, av.y, av.z, av.w};
            float wb[4] = {wv.x, wv.y, wv.z, wv.w};
#pragma unroll
            for (int i = 0; i < 4; ++i)
#pragma unroll
                for (int j = 0; j < 4; ++j)
                    acc[i][j] = fmaf(aa[i], wb[j], acc[i][j]);
        }
    }
#pragma unroll
    for (int i = 0; i < 4; ++i) {
        int row = rowBase + (ty << 2) + i;
        if (row >= cBS) continue;
        int b = row / cS, s = row % cS;
#pragma unroll
        for (int j = 0; j < 4; ++j) {
            int col = colBase + (tx << 2) + j;
            if (col >= cD) continue;
            int h = col / cHD, hd = col % cHD;
            Out[((size_t)(b * cH + h) * cS + s) * cHD + hd] = acc[i][j] + bias[col];
        }
    }
}

// ---------------- RoPE (in-place on q and k, layout (B*H, S, HD)) ----------------
__global__ __launch_bounds__(256) void rope_kernel(
    float* __restrict__ qd, float* __restrict__ kd, const float* __restrict__ cs)
{
    int idx = blockIdx.x * 256 + threadIdx.x;
    if (idx >= cB * cH * cS * 15) return;
    float* x = blockIdx.y ? kd : qd;
    int pair = idx % 15;
    int rs = idx / 15;
    int s = rs % cS;
    int bh = rs / cS;
    int b = bh / cH;
    int a = pair / 5, j = pair % 5;
    // 10000^(-j/5) = exp(-j * ln(10000)/5)
    float inv = __expf(-1.8420680743952367f * (float)j);
    float coord = cs[(b * cS + s) * 3 + a];
    float ang = coord * inv;
    float sn, co;
    sincosf(ang, &sn, &co);
    float* xp = x + ((size_t)bh * cS + s) * cHD + a * 10 + 2 * j;
    float x1 = xp[0], x2 = xp[1];
    xp[0] = x1 * co - x2 * sn;
    xp[1] = x1 * sn + x2 * co;
}

// ---------------- flash attention: 1 q-row per 8-lane group ----------------
__global__ __launch_bounds__(256) void attn_kernel(
    const float* __restrict__ q, const float* __restrict__ k,
    const float* __restrict__ v, float* __restrict__ out)
{
    __shared__ float Ks[64][36];
    __shared__ float Vs[64][36];
    const int bh = blockIdx.y;
    const int b = bh / cH, h = bh % cH;
    const int qbase = blockIdx.x * 32;
    const int tid = threadIdx.x;
    const int lane = tid & 63;
    const int wave = tid >> 6;
    const int qi = (wave << 3) + (lane >> 3);
    const int koff = lane & 7;
    const int qrow = qbase + qi;
    const bool active = qrow < cS;
    const float* kb = k + (size_t)bh * cS * cHD;
    const float* vb = v + (size_t)bh * cS * cHD;
    float qv[30];
    if (active) {
        const float* qp = q + ((size_t)bh * cS + qrow) * cHD;
#pragma unroll
        for (int d = 0; d < 30; ++d) qv[d] = qp[d];
    } else {
#pragma unroll
        for (int d = 0; d < 30; ++d) qv[d] = 0.f;
    }
    const bool qpast = qrow >= cPAST;
    float m = -3.0e38f, l = 0.f;
    float o[30];
#pragma unroll
    for (int d = 0; d < 30; ++d) o[d] = 0.f;
    const float scl = 0.18257418583505536f; // 1/sqrt(30)
    const int c0 = (qbase >= cPAST) ? 512 : 0; // skip fully-masked chunks
    for (int cstart = c0; cstart < cS; cstart += 64) {
        const int csz = min(64, cS - cstart);
        __syncthreads();
        for (int t = tid; t < csz * 30; t += 256) {
            int rr = t / 30, dd = t - rr * 30;
            Ks[rr][dd] = kb[cstart * 30 + t];
            Vs[rr][dd] = vb[cstart * 30 + t];
        }
        __syncthreads();
        if (active) {
            for (int kc = koff; kc < csz; kc += 8) {
                int kg = cstart + kc;
                float sc;
                if (qpast && kg < cPAST) sc = -3.0e38f;
                else {
                    float dot = 0.f;
                    const float4* kr = reinterpret_cast<const float4*>(&Ks[kc][0]);
#pragma unroll
                    for (int d4 = 0; d4 < 7; ++d4) {
                        float4 k4 = kr[d4];
                        dot = fmaf(qv[4 * d4 + 0], k4.x, dot);
                        dot = fmaf(qv[4 * d4 + 1], k4.y, dot);
                        dot = fmaf(qv[4 * d4 + 2], k4.z, dot);
                        dot = fmaf(qv[4 * d4 + 3], k4.w, dot);
                    }
                    float2 k2 = *reinterpret_cast<const float2*>(&Ks[kc][28]);
                    dot = fmaf(qv[28], k2.x, dot);
                    dot = fmaf(qv[29], k2.y, dot);
                    sc = dot * scl;
                }
                float mn = fmaxf(m, sc);
                float corr = __expf(m - mn);
                float p = __expf(sc - mn);
                l = l * corr + p;
                const float4* vr = reinterpret_cast<const float4*>(&Vs[kc][0]);
#pragma unroll
                for (int d4 = 0; d4 < 7; ++d4) {
                    float4 v4 = vr[d4];
                    o[4 * d4 + 0] = o[4 * d4 + 0] * corr + p * v4.x;
                    o[4 * d4 + 1] = o[4 * d4 + 1] * corr + p * v4.y;
                    o[4 * d4 + 2] = o[4 * d4 + 2] * corr + p * v4.z;
                    o[4 * d4 + 3] = o[4 * d4 + 3] * corr + p * v4.w;
                }
                float2 v2 = *reinterpret_cast<const float2*>(&Vs[kc][28]);
                o[28] = o[28] * corr + p * v2.x;
                o[29] = o[29] * corr + p * v2.y;
                m = mn;
            }
        }
    }
    // combine the 8 koff lanes that share a q-row
#pragma unroll
    for (int off = 1; off < 8; off <<= 1) {
        float m2 = __shfl_xor(m, off);
        float l2 = __shfl_xor(l, off);
        float mn = fmaxf(m, m2);
        float ca = __expf(m - mn);
        float cb = __expf(m2 - mn);
        l = l * ca + l2 * cb;
#pragma unroll
        for (int d = 0; d < 30; ++d) {
            float o2 = __shfl_xor(o[d], off);
            o[d] = o[d] * ca + o2 * cb;
        }
        m = mn;
    }
    if (active && koff == 0) {
        float inv = 1.0f / l;
        float* op = out + ((size_t)b * cS + qrow) * cD + h * cHD;
#pragma unroll
        for (int d = 0; d < 30; ++d) op[d] = o[d] * inv;
    }
}

// ---------------- LayerNorm: one row (240) per wave ----------------
__global__ __launch_bounds__(256) void ln_kernel(
    const float* __restrict__ x, const float* __restrict__ g,
    const float* __restrict__ be, float* __restrict__ y)
{
    int row = blockIdx.x * 4 + (threadIdx.x >> 6);
    int lane = threadIdx.x & 63;
    if (row >= cBS) return;
    const float* xr = x + (size_t)row * cD;
    float vals[4];
    float sum = 0.f;
#pragma unroll
    for (int j = 0; j < 4; ++j) {
        int d = lane + 64 * j;
        vals[j] = (d < cD) ? xr[d] : 0.f;
        sum += vals[j];
    }
#pragma unroll
    for (int off = 1; off < 64; off <<= 1) sum += __shfl_xor(sum, off);
    float mean = sum * (1.0f / cD);
    float vs = 0.f;
#pragma unroll
    for (int j = 0; j < 4; ++j) {
        int d = lane + 64 * j;
        float t = (d < cD) ? (vals[j] - mean) : 0.f;
        vs += t * t;
    }
#pragma unroll
    for (int off = 1; off < 64; off <<= 1) vs += __shfl_xor(vs, off);
    float rstd = rsqrtf(vs * (1.0f / cD) + EPSF);
    float* yr = y + (size_t)row * cD;
#pragma unroll
    for (int j = 0; j < 4; ++j) {
        int d = lane + 64 * j;
        if (d < cD) yr[d] = (vals[j] - mean) * rstd * g[d] + be[d];
    }
}

// ---------------- final copy: src[:, PAST:, :] -> out ----------------
__global__ __launch_bounds__(256) void copy_out_kernel(
    const float* __restrict__ src, float* __restrict__ out)
{
    int idx = blockIdx.x * 256 + threadIdx.x;
    constexpr int total = cB * (cS - cPAST) * cD;
    if (idx >= total) return;
    int d = idx % cD;
    int r = idx / cD;
    int b = r / (cS - cPAST);
    int i = r % (cS - cPAST);
    out[idx] = src[((size_t)b * cS + cPAST + i) * cD + d];
}

extern "C" void kernel_launch(void* const* d_in, const int* in_sizes, int n_in,
                              void* d_out, int out_size, void* d_ws, size_t ws_size,
                              hipStream_t stream) {
    (void)in_sizes; (void)n_in; (void)out_size; (void)ws_size;
    const float* hand_t       = (const float*)d_in[0];
    const float* head_t       = (const float*)d_in[1];
    const float* hand_m1      = (const float*)d_in[2];
    const float* head_m1      = (const float*)d_in[3];
    const float* c_hand_t     = (const float*)d_in[4];
    const float* c_head_t     = (const float*)d_in[5];
    const float* c_hand_m1    = (const float*)d_in[6];
    const float* c_head_m1    = (const float*)d_in[7];
    const float* state_t      = (const float*)d_in[8];
    const float* state_m1     = (const float*)d_in[9];
    const float* hand_pose_m1 = (const float*)d_in[10];
    const float* head_pose_m1 = (const float*)d_in[11];
    const float* hand_pose_t  = (const float*)d_in[12];
    const float* head_pose_t  = (const float*)d_in[13];
    const float* Wq = (const float*)d_in[14];
    const float* Wk = (const float*)d_in[15];
    const float* Wv = (const float*)d_in[16];
    const float* Wo = (const float*)d_in[17];
    const float* W1 = (const float*)d_in[18];
    const float* W2 = (const float*)d_in[19];
    const float* bq = (const float*)d_in[20];
    const float* bk = (const float*)d_in[21];
    const float* bv = (const float*)d_in[22];
    const float* bo = (const float*)d_in[23];
    const float* b1 = (const float*)d_in[24];
    const float* b2 = (const float*)d_in[25];
    const float* g1 = (const float*)d_in[26];
    const float* be1 = (const float*)d_in[27];
    const float* g2 = (const float*)d_in[28];
    const float* be2 = (const float*)d_in[29];

    float* ws = (float*)d_ws;
    float* srcb  = ws;                       // BS*D
    float* csb   = srcb  + (size_t)cBS * cD; // BS*3
    float* qb    = csb   + (size_t)cBS * 3;  // BS*D (as B,H,S,HD)
    float* kb    = qb    + (size_t)cBS * cD;
    float* vb    = kb    + (size_t)cBS * cD;
    float* attnb = vb    + (size_t)cBS * cD;
    float* resid = attnb + (size_t)cBS * cD;
    float* s2b   = resid + (size_t)cBS * cD;
    float* ffb   = s2b   + (size_t)cBS * cD; // BS*FF

    embed_kernel<<<(cBS * cD + 255) / 256, 256, 0, stream>>>(
        hand_t, head_t, hand_m1, head_m1, state_t, state_m1,
        hand_pose_m1, head_pose_m1, hand_pose_t, head_pose_t, srcb);
    coords_kernel<<<(cBS + 255) / 256, 256, 0, stream>>>(
        c_hand_t, c_head_t, c_hand_m1, c_head_m1, csb);

    const int mTiles = (cBS + 63) / 64; // 65
    for (int l = 0; l < cL; ++l) {
        const float* Wq_l = Wq + (size_t)l * cD * cD;
        const float* Wk_l = Wk + (size_t)l * cD * cD;
        const float* Wv_l = Wv + (size_t)l * cD * cD;
        const float* Wo_l = Wo + (size_t)l * cD * cD;
        const float* W1_l = W1 + (size_t)l * cFF * cD;
        const float* W2_l = W2 + (size_t)l * cD * cFF;
        const float* bq_l = bq + (size_t)l * cD;
        const float* bk_l = bk + (size_t)l * cD;
        const float* bv_l = bv + (size_t)l * cD;
        const float* bo_l = bo + (size_t)l * cD;
        const float* b1_l = b1 + (size_t)l * cFF;
        const float* b2_l = b2 + (size_t)l * cD;
        const float* g1_l = g1 + (size_t)l * cD;
        const float* be1_l = be1 + (size_t)l * cD;
        const float* g2_l = g2 + (size_t)l * cD;
        const float* be2_l = be2 + (size_t)l * cD;

        gemm_qkv<<<dim3(4, mTiles, 3), 256, 0, stream>>>(
            srcb, Wq_l, Wk_l, Wv_l, bq_l, bk_l, bv_l, qb, kb, vb);
        rope_kernel<<<dim3((cB * cH * cS * 15 + 255) / 256, 2), 256, 0, stream>>>(qb, kb, csb);
        attn_kernel<<<dim3((cS + 31) / 32, cB * cH), 256, 0, stream>>>(qb, kb, vb, attnb);
        gemm_bt<1><<<dim3(4, mTiles), 256, 0, stream>>>(
            attnb, Wo_l, bo_l, srcb, resid, cBS, cD, cD);
        ln_kernel<<<(cBS + 3) / 4, 256, 0, stream>>>(resid, g1_l, be1_l, s2b);
        gemm_bt<2><<<dim3(16, mTiles), 256, 0, stream>>>(
            s2b, W1_l, b1_l, nullptr, ffb, cBS, cFF, cD);
        gemm_bt<1><<<dim3(4, mTiles), 256, 0, stream>>>(
            ffb, W2_l, b2_l, s2b, resid, cBS, cD, cFF);
        ln_kernel<<<(cBS + 3) / 4, 256, 0, stream>>>(resid, g2_l, be2_l, srcb);
    }
    copy_out_kernel<<<(cB * (cS - cPAST) * cD + 255) / 256, 256, 0, stream>>>(
        srcb, (float*)d_out);
}

// Round 2
// 823.573 us; speedup vs baseline: 1.4799x; 1.4799x over previous
//
#include <hip/hip_runtime.h>
#include <cmath>

constexpr int cB = 4, cN = 256, cD = 240, cH = 8, cFF = 1024, cL = 4;
constexpr int cHD = 30, cS = 1030, cPAST = 515, cBS = cB * cS; // 4120
constexpr int cKp = 256;  // padded K for D-sized contractions
constexpr float EPSF = 1e-5f;

typedef __bf16 bf16x8 __attribute__((ext_vector_type(8)));
typedef float f32x4 __attribute__((ext_vector_type(4)));

__device__ inline unsigned short f2bf(float f) {
    unsigned int u = __builtin_bit_cast(unsigned int, f);
    unsigned int r = (u + 0x7fffu + ((u >> 16) & 1u)) >> 16;
    return (unsigned short)r;
}

// ---------------- weight convert + zero-pad: (L,R,C) f32 -> (L,Rp,Cp) bf16 ----------------
__global__ __launch_bounds__(256) void convert_pad(
    const float* __restrict__ in, unsigned short* __restrict__ out,
    int R, int C, int Rp, int Cp)
{
    int idx = blockIdx.x * 256 + threadIdx.x;
    int total = cL * Rp * Cp;
    if (idx >= total) return;
    int m = idx / (Rp * Cp);
    int rc = idx % (Rp * Cp);
    int r = rc / Cp, c = rc % Cp;
    float v = (r < R && c < C) ? in[((size_t)m * R + r) * C + c] : 0.f;
    out[idx] = f2bf(v);
}

// ---------------- zero the pad columns (240..255) of the bf16 activation buffers ----------------
__global__ __launch_bounds__(256) void zero_pad_kernel(
    unsigned short* __restrict__ a, unsigned short* __restrict__ b, unsigned short* __restrict__ c)
{
    int idx = blockIdx.x * 256 + threadIdx.x;
    if (idx >= cBS * 16) return;
    int r = idx / 16, j = idx % 16;
    a[(size_t)r * 256 + 240 + j] = 0;
    b[(size_t)r * 256 + 240 + j] = 0;
    c[(size_t)r * 256 + 240 + j] = 0;
}

// ---------------- embed: build src (BS x D) f32 + bf16 padded copy ----------------
__global__ __launch_bounds__(256) void embed_kernel(
    const float* __restrict__ hand_t, const float* __restrict__ head_t,
    const float* __restrict__ hand_m1, const float* __restrict__ head_m1,
    const float* __restrict__ state_t, const float* __restrict__ state_m1,
    const float* __restrict__ hand_pose_m1, const float* __restrict__ head_pose_m1,
    const float* __restrict__ hand_pose_t, const float* __restrict__ head_pose_t,
    float* __restrict__ src, unsigned short* __restrict__ sbf)
{
    int idx = blockIdx.x * 256 + threadIdx.x;
    if (idx >= cBS * cD) return;
    int d = idx % cD;
    int r = idx / cD;
    int b = r / cS, s = r % cS;
    const float* p; int off;
    if (s == 0)                  { p = state_m1;     off = b * cD + d; }
    else if (s == 1)             { p = hand_pose_m1; off = b * cD + d; }
    else if (s == 2)             { p = head_pose_m1; off = b * cD + d; }
    else if (s < 3 + cN)         { p = hand_m1;      off = (b * cN + (s - 3)) * cD + d; }
    else if (s < 3 + 2 * cN)     { p = head_m1;      off = (b * cN + (s - 3 - cN)) * cD + d; }
    else if (s == cPAST)         { p = state_t;      off = b * cD + d; }
    else if (s == cPAST + 1)     { p = hand_pose_t;  off = b * cD + d; }
    else if (s == cPAST + 2)     { p = head_pose_t;  off = b * cD + d; }
    else if (s < cPAST + 3 + cN) { p = hand_t;       off = (b * cN + (s - cPAST - 3)) * cD + d; }
    else                         { p = head_t;       off = (b * cN + (s - cPAST - 3 - cN)) * cD + d; }
    float v = p[off];
    src[idx] = v;
    sbf[(size_t)r * cKp + d] = f2bf(v);
}

// ---------------- coords ----------------
__global__ __launch_bounds__(256) void coords_kernel(
    const float* __restrict__ ch_t, const float* __restrict__ cd_t,
    const float* __restrict__ ch_m1, const float* __restrict__ cd_m1,
    float* __restrict__ cs)
{
    int r = blockIdx.x * 256 + threadIdx.x;
    if (r >= cBS) return;
    int b = r / cS, s = r % cS;
    float x = 0.f, y = 0.f, z = 0.f;
    const float* p = nullptr; int i = 0;
    if (s >= 3 && s < 3 + cN)                       { p = ch_m1; i = s - 3; }
    else if (s >= 3 + cN && s < 3 + 2 * cN)         { p = cd_m1; i = s - 3 - cN; }
    else if (s >= cPAST + 3 && s < cPAST + 3 + cN)  { p = ch_t;  i = s - cPAST - 3; }
    else if (s >= cPAST + 3 + cN)                   { p = cd_t;  i = s - cPAST - 3 - cN; }
    if (p) { x = p[(b * cN + i) * 3 + 0]; y = p[(b * cN + i) * 3 + 1]; z = p[(b * cN + i) * 3 + 2]; }
    cs[r * 3 + 0] = x; cs[r * 3 + 1] = y; cs[r * 3 + 2] = z;
}

// ================= MFMA GEMM core =================
// C = A(MxKa bf16) @ W(Np x Ka bf16)^T. Block tile 128x64, 4 waves, wave tile 64x32
// (4m x 2n frags of mfma_f32_16x16x32_bf16), BK=32, reg-staged dbuf, padded LDS [*][40].
#define GEMM_CORE(A_PTR, W_PTR, M_, KA_, NK_)                                                 \
    __shared__ unsigned short Al[128][40];                                                    \
    __shared__ unsigned short Bl[64][40];                                                     \
    const int tid = threadIdx.x;                                                              \
    const int lane = tid & 63;                                                                \
    const int w = tid >> 6;                                                                   \
    const int wm = w >> 1, wn = w & 1;                                                        \
    const int lrow = lane & 15, kq = lane >> 4;                                               \
    const int rowBase = blockIdx.y * 128;                                                     \
    const int colBase = blockIdx.x * 64;                                                      \
    const int sRow = tid >> 2;                                                                \
    const int sS = tid & 3;                                                                   \
    const int ar0 = min(rowBase + sRow, M_ - 1);                                              \
    const int ar1 = min(rowBase + sRow + 64, M_ - 1);                                         \
    const int wr = colBase + sRow;                                                            \
    const unsigned short* a0p = A_PTR + (size_t)ar0 * KA_ + sS * 8;                           \
    const unsigned short* a1p = A_PTR + (size_t)ar1 * KA_ + sS * 8;                           \
    const unsigned short* wp  = W_PTR + (size_t)wr * KA_ + sS * 8;                            \
    f32x4 acc[4][2] = {};                                                                     \
    int4 ra0 = *(const int4*)a0p;                                                             \
    int4 ra1 = *(const int4*)a1p;                                                             \
    int4 rb  = *(const int4*)wp;                                                              \
    for (int ks = 0; ks < NK_; ++ks) {                                                        \
        __syncthreads();                                                                      \
        *(int4*)&Al[sRow][sS * 8]      = ra0;                                                 \
        *(int4*)&Al[sRow + 64][sS * 8] = ra1;                                                 \
        *(int4*)&Bl[sRow][sS * 8]      = rb;                                                  \
        __syncthreads();                                                                      \
        if (ks + 1 < NK_) {                                                                   \
            int kk = (ks + 1) * 32;                                                           \
            ra0 = *(const int4*)(a0p + kk);                                                   \
            ra1 = *(const int4*)(a1p + kk);                                                   \
            rb  = *(const int4*)(wp + kk);                                                    \
        }                                                                                     \
        bf16x8 af[4], bfr[2];                                                                 \
        _Pragma("unroll")                                                                     \
        for (int i = 0; i < 4; ++i)                                                           \
            af[i] = *(const bf16x8*)&Al[wm * 64 + i * 16 + lrow][kq * 8];                     \
        _Pragma("unroll")                                                                     \
        for (int j = 0; j < 2; ++j)                                                           \
            bfr[j] = *(const bf16x8*)&Bl[wn * 32 + j * 16 + lrow][kq * 8];                    \
        _Pragma("unroll")                                                                     \
        for (int i = 0; i < 4; ++i)                                                           \
            _Pragma("unroll")                                                                 \
            for (int j = 0; j < 2; ++j)                                                       \
                acc[i][j] = __builtin_amdgcn_mfma_f32_16x16x32_bf16(af[i], bfr[j], acc[i][j], 0, 0, 0); \
    }

// EPI: 1 = +bias+residual -> f32 out (ld 240) ; 2 = gelu(+bias) -> bf16 out (ld 1024)
template<int EPI>
__global__ __launch_bounds__(256) void gemm_epi(
    const unsigned short* __restrict__ A, const unsigned short* __restrict__ W,
    const float* __restrict__ bias, const float* __restrict__ Rs,
    float* __restrict__ outF, unsigned short* __restrict__ outB,
    int M, int Nreal, int Ka, int nK)
{
    GEMM_CORE(A, W, M, Ka, nK)
#pragma unroll
    for (int i = 0; i < 4; ++i) {
#pragma unroll
        for (int j = 0; j < 2; ++j) {
            int col = colBase + wn * 32 + j * 16 + lrow;
            if (col >= Nreal) continue;
            float bcol = bias[col];
            f32x4 v = acc[i][j];
#pragma unroll
            for (int r = 0; r < 4; ++r) {
                int row = rowBase + wm * 64 + i * 16 + kq * 4 + r;
                if (row >= M) continue;
                float t = v[r] + bcol;
                if (EPI == 1) {
                    outF[(size_t)row * 240 + col] = t + Rs[(size_t)row * 240 + col];
                } else {
                    float gl = 0.5f * t * (1.0f + erff(t * 0.70710678118654752f));
                    outB[(size_t)row * 1024 + col] = f2bf(gl);
                }
            }
        }
    }
}

// QKV GEMM: z selects weight set; epilogue scatters f32 to (B,H,S,HD)
__global__ __launch_bounds__(256) void gemm_qkv_mfma(
    const unsigned short* __restrict__ A,
    const unsigned short* __restrict__ Wqp, const unsigned short* __restrict__ Wkp,
    const unsigned short* __restrict__ Wvp,
    const float* __restrict__ bq, const float* __restrict__ bk, const float* __restrict__ bv,
    float* __restrict__ qo, float* __restrict__ ko, float* __restrict__ vo)
{
    const unsigned short* Wsel; const float* bias; float* Out;
    if (blockIdx.z == 0)      { Wsel = Wqp; bias = bq; Out = qo; }
    else if (blockIdx.z == 1) { Wsel = Wkp; bias = bk; Out = ko; }
    else                      { Wsel = Wvp; bias = bv; Out = vo; }
    GEMM_CORE(A, Wsel, cBS, cKp, 8)
#pragma unroll
    for (int i = 0; i < 4; ++i) {
#pragma unroll
        for (int j = 0; j < 2; ++j) {
            int col = colBase + wn * 32 + j * 16 + lrow;
            if (col >= cD) continue;
            float bcol = bias[col];
            int h = col / cHD, hd = col % cHD;
            f32x4 v = acc[i][j];
#pragma unroll
            for (int r = 0; r < 4; ++r) {
                int row = rowBase + wm * 64 + i * 16 + kq * 4 + r;
                if (row >= cBS) continue;
                int b = row / cS, s = row % cS;
                Out[(((size_t)(b * cH + h)) * cS + s) * cHD + hd] = v[r] + bcol;
            }
        }
    }
}

// ---------------- RoPE (in-place on q and k, layout (B*H, S, HD)) ----------------
__global__ __launch_bounds__(256) void rope_kernel(
    float* __restrict__ qd, float* __restrict__ kd, const float* __restrict__ cs)
{
    int idx = blockIdx.x * 256 + threadIdx.x;
    if (idx >= cB * cH * cS * 15) return;
    float* x = blockIdx.y ? kd : qd;
    int pair = idx % 15;
    int rs = idx / 15;
    int s = rs % cS;
    int bh = rs / cS;
    int b = bh / cH;
    int a = pair / 5, j = pair % 5;
    float inv = __expf(-1.8420680743952367f * (float)j);
    float coord = cs[(b * cS + s) * 3 + a];
    float ang = coord * inv;
    float sn, co;
    sincosf(ang, &sn, &co);
    float* xp = x + ((size_t)bh * cS + s) * cHD + a * 10 + 2 * j;
    float x1 = xp[0], x2 = xp[1];
    xp[0] = x1 * co - x2 * sn;
    xp[1] = x1 * sn + x2 * co;
}

// ---------------- flash attention: 1 q-row per 8-lane group, tile-based rescale ----------------
__global__ __launch_bounds__(256) void attn_kernel(
    const float* __restrict__ q, const float* __restrict__ k,
    const float* __restrict__ v, unsigned short* __restrict__ outb)
{
    __shared__ float Ks[64][36];
    __shared__ float Vs[64][36];
    const int bh = blockIdx.y;
    const int b = bh / cH, h = bh % cH;
    const int qbase = blockIdx.x * 32;
    const int tid = threadIdx.x;
    const int lane = tid & 63;
    const int wave = tid >> 6;
    const int qi = (wave << 3) + (lane >> 3);
    const int koff = lane & 7;
    const int qrow = qbase + qi;
    const bool active = qrow < cS;
    const float* kb = k + (size_t)bh * cS * cHD;
    const float* vb = v + (size_t)bh * cS * cHD;
    float qv[30];
    if (active) {
        const float* qp = q + ((size_t)bh * cS + qrow) * cHD;
#pragma unroll
        for (int d = 0; d < 30; ++d) qv[d] = qp[d];
    } else {
#pragma unroll
        for (int d = 0; d < 30; ++d) qv[d] = 0.f;
    }
    const bool qpast = qrow >= cPAST;
    float m = -3.0e38f, l = 0.f;
    float o[30];
#pragma unroll
    for (int d = 0; d < 30; ++d) o[d] = 0.f;
    const float scl = 0.18257418583505536f; // 1/sqrt(30)
    const int c0 = (qbase >= cPAST) ? 512 : 0;
    for (int cstart = c0; cstart < cS; cstart += 64) {
        const int csz = min(64, cS - cstart);
        __syncthreads();
        for (int t = tid; t < csz * 30; t += 256) {
            int rr = t / 30, dd = t - rr * 30;
            Ks[rr][dd] = kb[cstart * 30 + t];
            Vs[rr][dd] = vb[cstart * 30 + t];
        }
        __syncthreads();
        if (!active) continue;
        if (qpast && cstart + 64 <= cPAST) continue;  // fully-masked tile for this row
        float s[8];
#pragma unroll
        for (int t = 0; t < 8; ++t) {
            s[t] = -3.0e38f;
            int kc = koff + 8 * t;
            if (kc < csz) {
                int kg = cstart + kc;
                if (!(qpast && kg < cPAST)) {
                    float dot = 0.f;
                    const float4* kr = reinterpret_cast<const float4*>(&Ks[kc][0]);
#pragma unroll
                    for (int d4 = 0; d4 < 7; ++d4) {
                        float4 k4 = kr[d4];
                        dot = fmaf(qv[4 * d4 + 0], k4.x, dot);
                        dot = fmaf(qv[4 * d4 + 1], k4.y, dot);
                        dot = fmaf(qv[4 * d4 + 2], k4.z, dot);
                        dot = fmaf(qv[4 * d4 + 3], k4.w, dot);
                    }
                    float2 k2 = *reinterpret_cast<const float2*>(&Ks[kc][28]);
                    dot = fmaf(qv[28], k2.x, dot);
                    dot = fmaf(qv[29], k2.y, dot);
                    s[t] = dot * scl;
                }
            }
        }
        float mx = m;
#pragma unroll
        for (int t = 0; t < 8; ++t) mx = fmaxf(mx, s[t]);
        float corr = __expf(m - mx);
        m = mx;
        float psum = 0.f;
#pragma unroll
        for (int t = 0; t < 8; ++t) { s[t] = __expf(s[t] - mx); psum += s[t]; }
        l = l * corr + psum;
#pragma unroll
        for (int d = 0; d < 30; ++d) o[d] *= corr;
#pragma unroll
        for (int t = 0; t < 8; ++t) {
            int kc = koff + 8 * t;
            if (kc >= csz) break;
            float pt = s[t];
            const float4* vr = reinterpret_cast<const float4*>(&Vs[kc][0]);
#pragma unroll
            for (int d4 = 0; d4 < 7; ++d4) {
                float4 v4 = vr[d4];
                o[4 * d4 + 0] = fmaf(pt, v4.x, o[4 * d4 + 0]);
                o[4 * d4 + 1] = fmaf(pt, v4.y, o[4 * d4 + 1]);
                o[4 * d4 + 2] = fmaf(pt, v4.z, o[4 * d4 + 2]);
                o[4 * d4 + 3] = fmaf(pt, v4.w, o[4 * d4 + 3]);
            }
            float2 v2 = *reinterpret_cast<const float2*>(&Vs[kc][28]);
            o[28] = fmaf(pt, v2.x, o[28]);
            o[29] = fmaf(pt, v2.y, o[29]);
        }
    }
#pragma unroll
    for (int off = 1; off < 8; off <<= 1) {
        float m2 = __shfl_xor(m, off);
        float l2 = __shfl_xor(l, off);
        float mn = fmaxf(m, m2);
        float ca = __expf(m - mn);
        float cb = __expf(m2 - mn);
        l = l * ca + l2 * cb;
#pragma unroll
        for (int d = 0; d < 30; ++d) {
            float o2 = __shfl_xor(o[d], off);
            o[d] = o[d] * ca + o2 * cb;
        }
        m = mn;
    }
    if (active && koff == 0) {
        float inv = 1.0f / l;
        unsigned short* op = outb + ((size_t)b * cS + qrow) * cKp + h * cHD;
#pragma unroll
        for (int d = 0; d < 30; ++d) op[d] = f2bf(o[d] * inv);
    }
}

// ---------------- LayerNorm: one row (240) per wave; writes f32 + padded bf16 ----------------
__global__ __launch_bounds__(256) void ln_kernel(
    const float* __restrict__ x, const float* __restrict__ g,
    const float* __restrict__ be, float* __restrict__ y, unsigned short* __restrict__ ybf)
{
    int row = blockIdx.x * 4 + (threadIdx.x >> 6);
    int lane = threadIdx.x & 63;
    if (row >= cBS) return;
    const float* xr = x + (size_t)row * cD;
    float vals[4];
    float sum = 0.f;
#pragma unroll
    for (int j = 0; j < 4; ++j) {
        int d = lane + 64 * j;
        vals[j] = (d < cD) ? xr[d] : 0.f;
        sum += vals[j];
    }
#pragma unroll
    for (int off = 1; off < 64; off <<= 1) sum += __shfl_xor(sum, off);
    float mean = sum * (1.0f / cD);
    float vs = 0.f;
#pragma unroll
    for (int j = 0; j < 4; ++j) {
        int d = lane + 64 * j;
        float t = (d < cD) ? (vals[j] - mean) : 0.f;
        vs += t * t;
    }
#pragma unroll
    for (int off = 1; off < 64; off <<= 1) vs += __shfl_xor(vs, off);
    float rstd = rsqrtf(vs * (1.0f / cD) + EPSF);
    float* yr = y + (size_t)row * cD;
    unsigned short* br = ybf + (size_t)row * cKp;
#pragma unroll
    for (int j = 0; j < 4; ++j) {
        int d = lane + 64 * j;
        if (d < cD) {
            float r = (vals[j] - mean) * rstd * g[d] + be[d];
            yr[d] = r;
            br[d] = f2bf(r);
        }
    }
}

// ---------------- final copy ----------------
__global__ __launch_bounds__(256) void copy_out_kernel(
    const float* __restrict__ src, float* __restrict__ out)
{
    int idx = blockIdx.x * 256 + threadIdx.x;
    constexpr int total = cB * (cS - cPAST) * cD;
    if (idx >= total) return;
    int d = idx % cD;
    int r = idx / cD;
    int b = r / (cS - cPAST);
    int i = r % (cS - cPAST);
    out[idx] = src[((size_t)b * cS + cPAST + i) * cD + d];
}

extern "C" void kernel_launch(void* const* d_in, const int* in_sizes, int n_in,
                              void* d_out, int out_size, void* d_ws, size_t ws_size,
                              hipStream_t stream) {
    (void)in_sizes; (void)n_in; (void)out_size; (void)ws_size;
    const float* hand_t       = (const float*)d_in[0];
    const float* head_t       = (const float*)d_in[1];
    const float* hand_m1      = (const float*)d_in[2];
    const float* head_m1      = (const float*)d_in[3];
    const float* c_hand_t     = (const float*)d_in[4];
    const float* c_head_t     = (const float*)d_in[5];
    const float* c_hand_m1    = (const float*)d_in[6];
    const float* c_head_m1    = (const float*)d_in[7];
    const float* state_t      = (const float*)d_in[8];
    const float* state_m1     = (const float*)d_in[9];
    const float* hand_pose_m1 = (const float*)d_in[10];
    const float* head_pose_m1 = (const float*)d_in[11];
    const float* hand_pose_t  = (const float*)d_in[12];
    const float* head_pose_t  = (const float*)d_in[13];
    const float* Wq = (const float*)d_in[14];
    const float* Wk = (const float*)d_in[15];
    const float* Wv = (const float*)d_in[16];
    const float* Wo = (const float*)d_in[17];
    const float* W1 = (const float*)d_in[18];
    const float* W2 = (const float*)d_in[19];
    const float* bq = (const float*)d_in[20];
    const float* bk = (const float*)d_in[21];
    const float* bv = (const float*)d_in[22];
    const float* bo = (const float*)d_in[23];
    const float* b1 = (const float*)d_in[24];
    const float* b2 = (const float*)d_in[25];
    const float* g1 = (const float*)d_in[26];
    const float* be1 = (const float*)d_in[27];
    const float* g2 = (const float*)d_in[28];
    const float* be2 = (const float*)d_in[29];

    // ---- workspace layout ----
    char* p = (char*)d_ws;
    auto alloc_f = [&](size_t n) { float* r = (float*)p; p += n * sizeof(float); return r; };
    auto alloc_h = [&](size_t n) { unsigned short* r = (unsigned short*)p; p += n * sizeof(unsigned short); return r; };
    float* srcb  = alloc_f((size_t)cBS * cD);
    float* csb   = alloc_f((size_t)cBS * 4);
    float* qb    = alloc_f((size_t)cBS * cD);
    float* kb    = alloc_f((size_t)cBS * cD);
    float* vb    = alloc_f((size_t)cBS * cD);
    float* resid = alloc_f((size_t)cBS * cD);
    float* s2b   = alloc_f((size_t)cBS * cD);
    unsigned short* src_bf  = alloc_h((size_t)cBS * cKp);
    unsigned short* s2_bf   = alloc_h((size_t)cBS * cKp);
    unsigned short* attn_bf = alloc_h((size_t)cBS * cKp);
    unsigned short* ff_bf   = alloc_h((size_t)cBS * cFF);
    unsigned short* wq_p = alloc_h((size_t)cL * 256 * 256);
    unsigned short* wk_p = alloc_h((size_t)cL * 256 * 256);
    unsigned short* wv_p = alloc_h((size_t)cL * 256 * 256);
    unsigned short* wo_p = alloc_h((size_t)cL * 256 * 256);
    unsigned short* w1_p = alloc_h((size_t)cL * 1024 * 256);
    unsigned short* w2_p = alloc_h((size_t)cL * 256 * 1024);

    // ---- weight conversion (runs every launch; cheap) ----
    {
        int t1 = cL * 256 * 256;
        convert_pad<<<(t1 + 255) / 256, 256, 0, stream>>>(Wq, wq_p, 240, 240, 256, 256);
        convert_pad<<<(t1 + 255) / 256, 256, 0, stream>>>(Wk, wk_p, 240, 240, 256, 256);
        convert_pad<<<(t1 + 255) / 256, 256, 0, stream>>>(Wv, wv_p, 240, 240, 256, 256);
        convert_pad<<<(t1 + 255) / 256, 256, 0, stream>>>(Wo, wo_p, 240, 240, 256, 256);
        int t2 = cL * 1024 * 256;
        convert_pad<<<(t2 + 255) / 256, 256, 0, stream>>>(W1, w1_p, 1024, 240, 1024, 256);
        convert_pad<<<(t2 + 255) / 256, 256, 0, stream>>>(W2, w2_p, 240, 1024, 256, 1024);
    }
    zero_pad_kernel<<<(cBS * 16 + 255) / 256, 256, 0, stream>>>(src_bf, s2_bf, attn_bf);

    embed_kernel<<<(cBS * cD + 255) / 256, 256, 0, stream>>>(
        hand_t, head_t, hand_m1, head_m1, state_t, state_m1,
        hand_pose_m1, head_pose_m1, hand_pose_t, head_pose_t, srcb, src_bf);
    coords_kernel<<<(cBS + 255) / 256, 256, 0, stream>>>(
        c_hand_t, c_head_t, c_hand_m1, c_head_m1, csb);

    const int mTiles = (cBS + 127) / 128; // 33
    for (int l = 0; l < cL; ++l) {
        const unsigned short* wq_l = wq_p + (size_t)l * 256 * 256;
        const unsigned short* wk_l = wk_p + (size_t)l * 256 * 256;
        const unsigned short* wv_l = wv_p + (size_t)l * 256 * 256;
        const unsigned short* wo_l = wo_p + (size_t)l * 256 * 256;
        const unsigned short* w1_l = w1_p + (size_t)l * 1024 * 256;
        const unsigned short* w2_l = w2_p + (size_t)l * 256 * 1024;
        const float* bq_l = bq + (size_t)l * cD;
        const float* bk_l = bk + (size_t)l * cD;
        const float* bv_l = bv + (size_t)l * cD;
        const float* bo_l = bo + (size_t)l * cD;
        const float* b1_l = b1 + (size_t)l * cFF;
        const float* b2_l = b2 + (size_t)l * cD;
        const float* g1_l = g1 + (size_t)l * cD;
        const float* be1_l = be1 + (size_t)l * cD;
        const float* g2_l = g2 + (size_t)l * cD;
        const float* be2_l = be2 + (size_t)l * cD;

        gemm_qkv_mfma<<<dim3(4, mTiles, 3), 256, 0, stream>>>(
            src_bf, wq_l, wk_l, wv_l, bq_l, bk_l, bv_l, qb, kb, vb);
        rope_kernel<<<dim3((cB * cH * cS * 15 + 255) / 256, 2), 256, 0, stream>>>(qb, kb, csb);
        attn_kernel<<<dim3((cS + 31) / 32, cB * cH), 256, 0, stream>>>(qb, kb, vb, attn_bf);
        gemm_epi<1><<<dim3(4, mTiles), 256, 0, stream>>>(
            attn_bf, wo_l, bo_l, srcb, resid, nullptr, cBS, cD, cKp, 8);
        ln_kernel<<<(cBS + 3) / 4, 256, 0, stream>>>(resid, g1_l, be1_l, s2b, s2_bf);
        gemm_epi<2><<<dim3(16, mTiles), 256, 0, stream>>>(
            s2_bf, w1_l, b1_l, nullptr, nullptr, ff_bf, cBS, cFF, cKp, 8);
        gemm_epi<1><<<dim3(4, mTiles), 256, 0, stream>>>(
            ff_bf, w2_l, b2_l, s2b, resid, nullptr, cBS, cD, cFF, 32);
        ln_kernel<<<(cBS + 3) / 4, 256, 0, stream>>>(resid, g2_l, be2_l, srcb, src_bf);
    }
    copy_out_kernel<<<(cB * (cS - cPAST) * cD + 255) / 256, 256, 0, stream>>>(
        srcb, (float*)d_out);
}

// Round 3
// 498.896 us; speedup vs baseline: 2.4430x; 1.6508x over previous
//
#include <hip/hip_runtime.h>
#include <cmath>

constexpr int cB = 4, cN = 256, cD = 240, cH = 8, cFF = 1024, cL = 4;
constexpr int cHD = 30, cS = 1030, cPAST = 515, cBS = cB * cS; // 4120
constexpr int cKp = 256;   // padded K for D-sized contractions
constexpr int cSP = 1088;  // padded sequence for attention buffers
constexpr float EPSF = 1e-5f;

typedef __bf16 bf16x8 __attribute__((ext_vector_type(8)));
typedef float f32x4 __attribute__((ext_vector_type(4)));

__device__ inline unsigned short f2bf(float f) {
    unsigned int u = __builtin_bit_cast(unsigned int, f);
    unsigned int r = (u + 0x7fffu + ((u >> 16) & 1u)) >> 16;
    return (unsigned short)r;
}

// ---------------- all weights convert + zero-pad, one dispatch ----------------
// region A: Wq,Wk,Wv,Wo (L,240,240)->(L,256,256) at wqkv (4 consecutive)
// region B: W1 (L,1024,240)->(L,1024,256) ; region C: W2 (L,240,1024)->(L,256,1024)
__global__ __launch_bounds__(256) void convert_all(
    const float* __restrict__ Wq, const float* __restrict__ Wk,
    const float* __restrict__ Wv, const float* __restrict__ Wo,
    const float* __restrict__ W1, const float* __restrict__ W2,
    unsigned short* __restrict__ wqkv, unsigned short* __restrict__ w1p,
    unsigned short* __restrict__ w2p)
{
    int idx = blockIdx.x * 256 + threadIdx.x;
    if (idx < 4 * 262144) {
        int which = idx >> 18;
        const float* W = (which == 0) ? Wq : (which == 1) ? Wk : (which == 2) ? Wv : Wo;
        int rem = idx & 262143;
        int m = rem >> 16;
        int rc = rem & 65535;
        int r = rc >> 8, c = rc & 255;
        float v = (r < 240 && c < 240) ? W[((size_t)m * 240 + r) * 240 + c] : 0.f;
        wqkv[idx] = f2bf(v);
    } else if (idx < 4 * 262144 + 1048576) {
        int rem = idx - 4 * 262144;
        int m = rem >> 18;
        int rc = rem & 262143;
        int r = rc >> 8, c = rc & 255;
        float v = (c < 240) ? W1[((size_t)m * 1024 + r) * 240 + c] : 0.f;
        w1p[rem] = f2bf(v);
    } else if (idx < 4 * 262144 + 2 * 1048576) {
        int rem = idx - 4 * 262144 - 1048576;
        int m = rem >> 18;
        int rc = rem & 262143;
        int r = rc >> 10, c = rc & 1023;
        float v = (r < 240) ? W2[((size_t)m * 240 + r) * 1024 + c] : 0.f;
        w2p[rem] = f2bf(v);
    }
}

// ---------------- zero-init: q/k/vT bf16 span + pad cols of activation bufs ----------------
__global__ __launch_bounds__(256) void zero_init(
    unsigned int* __restrict__ span, int n32,
    unsigned short* __restrict__ a, unsigned short* __restrict__ b,
    unsigned short* __restrict__ c)
{
    int idx = blockIdx.x * 256 + threadIdx.x;
    if (idx < n32) span[idx] = 0u;
    if (idx < cBS * 8) {
        int r = idx >> 3, j = idx & 7;
        ((unsigned int*)(a + (size_t)r * 256 + 240))[j] = 0u;
        ((unsigned int*)(b + (size_t)r * 256 + 240))[j] = 0u;
        ((unsigned int*)(c + (size_t)r * 256 + 240))[j] = 0u;
    }
}

// ---------------- embed: build src (BS x D) f32 + bf16 padded copy ----------------
__global__ __launch_bounds__(256) void embed_kernel(
    const float* __restrict__ hand_t, const float* __restrict__ head_t,
    const float* __restrict__ hand_m1, const float* __restrict__ head_m1,
    const float* __restrict__ state_t, const float* __restrict__ state_m1,
    const float* __restrict__ hand_pose_m1, const float* __restrict__ head_pose_m1,
    const float* __restrict__ hand_pose_t, const float* __restrict__ head_pose_t,
    float* __restrict__ src, unsigned short* __restrict__ sbf)
{
    int idx = blockIdx.x * 256 + threadIdx.x;
    if (idx >= cBS * cD) return;
    int d = idx % cD;
    int r = idx / cD;
    int b = r / cS, s = r % cS;
    const float* p; int off;
    if (s == 0)                  { p = state_m1;     off = b * cD + d; }
    else if (s == 1)             { p = hand_pose_m1; off = b * cD + d; }
    else if (s == 2)             { p = head_pose_m1; off = b * cD + d; }
    else if (s < 3 + cN)         { p = hand_m1;      off = (b * cN + (s - 3)) * cD + d; }
    else if (s < 3 + 2 * cN)     { p = head_m1;      off = (b * cN + (s - 3 - cN)) * cD + d; }
    else if (s == cPAST)         { p = state_t;      off = b * cD + d; }
    else if (s == cPAST + 1)     { p = hand_pose_t;  off = b * cD + d; }
    else if (s == cPAST + 2)     { p = head_pose_t;  off = b * cD + d; }
    else if (s < cPAST + 3 + cN) { p = hand_t;       off = (b * cN + (s - cPAST - 3)) * cD + d; }
    else                         { p = head_t;       off = (b * cN + (s - cPAST - 3 - cN)) * cD + d; }
    float v = p[off];
    src[idx] = v;
    sbf[(size_t)r * cKp + d] = f2bf(v);
}

// ---------------- coords ----------------
__global__ __launch_bounds__(256) void coords_kernel(
    const float* __restrict__ ch_t, const float* __restrict__ cd_t,
    const float* __restrict__ ch_m1, const float* __restrict__ cd_m1,
    float* __restrict__ cs)
{
    int r = blockIdx.x * 256 + threadIdx.x;
    if (r >= cBS) return;
    int b = r / cS, s = r % cS;
    float x = 0.f, y = 0.f, z = 0.f;
    const float* p = nullptr; int i = 0;
    if (s >= 3 && s < 3 + cN)                       { p = ch_m1; i = s - 3; }
    else if (s >= 3 + cN && s < 3 + 2 * cN)         { p = cd_m1; i = s - 3 - cN; }
    else if (s >= cPAST + 3 && s < cPAST + 3 + cN)  { p = ch_t;  i = s - cPAST - 3; }
    else if (s >= cPAST + 3 + cN)                   { p = cd_t;  i = s - cPAST - 3 - cN; }
    if (p) { x = p[(b * cN + i) * 3 + 0]; y = p[(b * cN + i) * 3 + 1]; z = p[(b * cN + i) * 3 + 2]; }
    cs[r * 3 + 0] = x; cs[r * 3 + 1] = y; cs[r * 3 + 2] = z;
}

// ================= MFMA GEMM core (validated round 2) =================
#define GEMM_CORE(A_PTR, W_PTR, M_, KA_, NK_)                                                 \
    __shared__ unsigned short Al[128][40];                                                    \
    __shared__ unsigned short Bl[64][40];                                                     \
    const int tid = threadIdx.x;                                                              \
    const int lane = tid & 63;                                                                \
    const int w = tid >> 6;                                                                   \
    const int wm = w >> 1, wn = w & 1;                                                        \
    const int lrow = lane & 15, kq = lane >> 4;                                               \
    const int rowBase = blockIdx.y * 128;                                                     \
    const int colBase = blockIdx.x * 64;                                                      \
    const int sRow = tid >> 2;                                                                \
    const int sS = tid & 3;                                                                   \
    const int ar0 = min(rowBase + sRow, M_ - 1);                                              \
    const int ar1 = min(rowBase + sRow + 64, M_ - 1);                                         \
    const int wr = colBase + sRow;                                                            \
    const unsigned short* a0p = A_PTR + (size_t)ar0 * KA_ + sS * 8;                           \
    const unsigned short* a1p = A_PTR + (size_t)ar1 * KA_ + sS * 8;                           \
    const unsigned short* wp  = W_PTR + (size_t)wr * KA_ + sS * 8;                            \
    f32x4 acc[4][2] = {};                                                                     \
    int4 ra0 = *(const int4*)a0p;                                                             \
    int4 ra1 = *(const int4*)a1p;                                                             \
    int4 rb  = *(const int4*)wp;                                                              \
    for (int ks = 0; ks < NK_; ++ks) {                                                        \
        __syncthreads();                                                                      \
        *(int4*)&Al[sRow][sS * 8]      = ra0;                                                 \
        *(int4*)&Al[sRow + 64][sS * 8] = ra1;                                                 \
        *(int4*)&Bl[sRow][sS * 8]      = rb;                                                  \
        __syncthreads();                                                                      \
        if (ks + 1 < NK_) {                                                                   \
            int kk = (ks + 1) * 32;                                                           \
            ra0 = *(const int4*)(a0p + kk);                                                   \
            ra1 = *(const int4*)(a1p + kk);                                                   \
            rb  = *(const int4*)(wp + kk);                                                    \
        }                                                                                     \
        bf16x8 af[4], bfr[2];                                                                 \
        _Pragma("unroll")                                                                     \
        for (int i = 0; i < 4; ++i)                                                           \
            af[i] = *(const bf16x8*)&Al[wm * 64 + i * 16 + lrow][kq * 8];                     \
        _Pragma("unroll")                                                                     \
        for (int j = 0; j < 2; ++j)                                                           \
            bfr[j] = *(const bf16x8*)&Bl[wn * 32 + j * 16 + lrow][kq * 8];                    \
        _Pragma("unroll")                                                                     \
        for (int i = 0; i < 4; ++i)                                                           \
            _Pragma("unroll")                                                                 \
            for (int j = 0; j < 2; ++j)                                                       \
                acc[i][j] = __builtin_amdgcn_mfma_f32_16x16x32_bf16(af[i], bfr[j], acc[i][j], 0, 0, 0); \
    }

// EPI: 1 = +bias+residual -> f32 out (ld 240) ; 2 = gelu(+bias) -> bf16 out (ld 1024)
template<int EPI>
__global__ __launch_bounds__(256) void gemm_epi(
    const unsigned short* __restrict__ A, const unsigned short* __restrict__ W,
    const float* __restrict__ bias, const float* __restrict__ Rs,
    float* __restrict__ outF, unsigned short* __restrict__ outB,
    int M, int Nreal, int Ka, int nK)
{
    GEMM_CORE(A, W, M, Ka, nK)
#pragma unroll
    for (int i = 0; i < 4; ++i) {
#pragma unroll
        for (int j = 0; j < 2; ++j) {
            int col = colBase + wn * 32 + j * 16 + lrow;
            if (col >= Nreal) continue;
            float bcol = bias[col];
            f32x4 v = acc[i][j];
#pragma unroll
            for (int r = 0; r < 4; ++r) {
                int row = rowBase + wm * 64 + i * 16 + kq * 4 + r;
                if (row >= M) continue;
                float t = v[r] + bcol;
                if (EPI == 1) {
                    outF[(size_t)row * 240 + col] = t + Rs[(size_t)row * 240 + col];
                } else {
                    float gl = 0.5f * t * (1.0f + erff(t * 0.70710678118654752f));
                    outB[(size_t)row * 1024 + col] = f2bf(gl);
                }
            }
        }
    }
}

// ---------------- QKV GEMM with fused RoPE; writes bf16 q,k (BH,SP,32) and V^T (BH,32,SP) ----
__global__ __launch_bounds__(256) void gemm_qkv_rope(
    const unsigned short* __restrict__ A,
    const unsigned short* __restrict__ Wqp, const unsigned short* __restrict__ Wkp,
    const unsigned short* __restrict__ Wvp,
    const float* __restrict__ bq, const float* __restrict__ bk, const float* __restrict__ bv,
    const float* __restrict__ cs,
    unsigned short* __restrict__ qbf, unsigned short* __restrict__ kbf,
    unsigned short* __restrict__ vtbf)
{
    const int z = blockIdx.z;
    const unsigned short* Wsel = (z == 0) ? Wqp : (z == 1) ? Wkp : Wvp;
    const float* bias = (z == 0) ? bq : (z == 1) ? bk : bv;
    GEMM_CORE(A, Wsel, cBS, cKp, 8)
#pragma unroll
    for (int i = 0; i < 4; ++i) {
#pragma unroll
        for (int j = 0; j < 2; ++j) {
            int col = colBase + wn * 32 + j * 16 + lrow;
            bool colok = col < cD;
            int cc = colok ? col : 0;
            float bcol = colok ? bias[cc] : 0.f;
            int hh = cc / cHD, hd = cc % cHD;
            int a3 = hd / 10, jj = (hd % 10) >> 1;
            float invf = __expf(-1.8420680743952367f * (float)jj);
            f32x4 vv = acc[i][j];
#pragma unroll
            for (int r = 0; r < 4; ++r) {
                int row = rowBase + wm * 64 + i * 16 + kq * 4 + r;
                bool rowok = row < cBS;
                int rowc = rowok ? row : 0;
                float val = vv[r] + bcol;
                float pval = __shfl_xor(val, 1);   // partner col (pairs are adjacent lanes)
                int b = rowc / cS, s = rowc - b * cS;
                size_t bh = (size_t)(b * cH + hh);
                if (z == 2) {
                    if (colok && rowok)
                        vtbf[(bh * 32 + hd) * cSP + s] = f2bf(val);
                } else {
                    float ang = cs[rowc * 3 + a3] * invf;
                    float sn, co;
                    __sincosf(ang, &sn, &co);
                    float outv = (hd & 1) ? (pval * sn + val * co) : (val * co - pval * sn);
                    if (colok && rowok) {
                        unsigned short* dst = (z == 0) ? qbf : kbf;
                        dst[(bh * cSP + s) * 32 + hd] = f2bf(outv);
                    }
                }
            }
        }
    }
}

// ---------------- MFMA flash attention: 4 independent waves x 16 q-rows, no barriers -------
__global__ __launch_bounds__(256) void attn_mfma(
    const unsigned short* __restrict__ qbf, const unsigned short* __restrict__ kbf,
    const unsigned short* __restrict__ vtbf, unsigned short* __restrict__ outb)
{
    __shared__ unsigned short Pl[4][16][72];  // per-wave P^T staging (16B-aligned rows)
    const int tid = threadIdx.x, lane = tid & 63, w = tid >> 6;
    const int bh = blockIdx.y, b = bh >> 3, h = bh & 7;
    const int qbase = blockIdx.x * 64;
    const int q0 = qbase + w * 16;
    const int lr = lane & 15, lg = lane >> 4;
    const float scl = 0.18257418583505536f; // 1/sqrt(30)
    const f32x4 czero = {0.f, 0.f, 0.f, 0.f};
    bf16x8 qf = *(const bf16x8*)&qbf[((size_t)bh * cSP + q0 + lr) * 32 + lg * 8];
    float m[4], l[4];
    f32x4 o0 = czero, o1 = czero;
#pragma unroll
    for (int r = 0; r < 4; ++r) { m[r] = -3.0e38f; l[r] = 0.f; }
    const int kstart = (qbase >= 576) ? 512 : 0;  // rows >= 515 skip fully-masked tiles
    const int qrow_b = q0 + lg * 4;
    for (int kb = kstart; kb < cS; kb += 64) {
        f32x4 c[4];
#pragma unroll
        for (int t = 0; t < 4; ++t) {
            bf16x8 kf = *(const bf16x8*)&kbf[((size_t)bh * cSP + kb + 16 * t + lr) * 32 + lg * 8];
            c[t] = __builtin_amdgcn_mfma_f32_16x16x32_bf16(qf, kf, czero, 0, 0, 0);
        }
        // scale + mask (C layout: col=key=lr per subtile, row=lg*4+r)
#pragma unroll
        for (int t = 0; t < 4; ++t) {
            int key = kb + 16 * t + lr;
            bool koob = key >= cS;
            bool kpast = key < cPAST;
#pragma unroll
            for (int r = 0; r < 4; ++r) {
                float s = c[t][r] * scl;
                bool msk = koob || ((qrow_b + r >= cPAST) && kpast);
                c[t][r] = msk ? -3.0e38f : s;
            }
        }
        float mx[4];
#pragma unroll
        for (int r = 0; r < 4; ++r)
            mx[r] = fmaxf(fmaxf(c[0][r], c[1][r]), fmaxf(c[2][r], c[3][r]));
#pragma unroll
        for (int off = 1; off < 16; off <<= 1)
#pragma unroll
            for (int r = 0; r < 4; ++r)
                mx[r] = fmaxf(mx[r], __shfl_xor(mx[r], off));
        float corr[4], me[4], ps[4];
#pragma unroll
        for (int r = 0; r < 4; ++r) {
            float mn = fmaxf(m[r], mx[r]);
            corr[r] = __expf(m[r] - mn);
            m[r] = mn;
            me[r] = fmaxf(mn, -1.0e30f);  // floor: all-masked tile -> P = exp(-3e38) = 0
            ps[r] = 0.f;
        }
#pragma unroll
        for (int t = 0; t < 4; ++t)
#pragma unroll
            for (int r = 0; r < 4; ++r) {
                float p = __expf(c[t][r] - me[r]);
                c[t][r] = p;
                ps[r] += p;
            }
#pragma unroll
        for (int off = 1; off < 16; off <<= 1)
#pragma unroll
            for (int r = 0; r < 4; ++r)
                ps[r] += __shfl_xor(ps[r], off);
#pragma unroll
        for (int r = 0; r < 4; ++r) {
            l[r] = l[r] * corr[r] + ps[r];
            o0[r] *= corr[r];
            o1[r] *= corr[r];
        }
        // write P (bf16) to per-wave LDS, transposed to A-fragment layout
#pragma unroll
        for (int t = 0; t < 4; ++t)
#pragma unroll
            for (int r = 0; r < 4; ++r)
                Pl[w][lg * 4 + r][16 * t + lr] = f2bf(c[t][r]);
        // PV: O(16x32) += P(16x64) @ V(64x32), V^T read direct from global
#pragma unroll
        for (int c2 = 0; c2 < 2; ++c2) {
            bf16x8 pa  = *(const bf16x8*)&Pl[w][lr][c2 * 32 + lg * 8];
            bf16x8 bv0 = *(const bf16x8*)&vtbf[((size_t)bh * 32 + lr) * cSP + kb + c2 * 32 + lg * 8];
            bf16x8 bv1 = *(const bf16x8*)&vtbf[((size_t)bh * 32 + 16 + lr) * cSP + kb + c2 * 32 + lg * 8];
            o0 = __builtin_amdgcn_mfma_f32_16x16x32_bf16(pa, bv0, o0, 0, 0, 0);
            o1 = __builtin_amdgcn_mfma_f32_16x16x32_bf16(pa, bv1, o1, 0, 0, 0);
        }
    }
#pragma unroll
    for (int r = 0; r < 4; ++r) {
        int q = qrow_b + r;
        if (q >= cS) continue;
        float inv = 1.0f / l[r];
        unsigned short* op = outb + ((size_t)(b * cS + q)) * cKp + h * cHD;
        op[lr] = f2bf(o0[r] * inv);
        if (lr < 14) op[16 + lr] = f2bf(o1[r] * inv);
    }
}

// ---------------- LayerNorm: one row (240) per wave; writes f32 + padded bf16 ----------------
__global__ __launch_bounds__(256) void ln_kernel(
    const float* __restrict__ x, const float* __restrict__ g,
    const float* __restrict__ be, float* __restrict__ y, unsigned short* __restrict__ ybf)
{
    int row = blockIdx.x * 4 + (threadIdx.x >> 6);
    int lane = threadIdx.x & 63;
    if (row >= cBS) return;
    const float* xr = x + (size_t)row * cD;
    float vals[4];
    float sum = 0.f;
#pragma unroll
    for (int j = 0; j < 4; ++j) {
        int d = lane + 64 * j;
        vals[j] = (d < cD) ? xr[d] : 0.f;
        sum += vals[j];
    }
#pragma unroll
    for (int off = 1; off < 64; off <<= 1) sum += __shfl_xor(sum, off);
    float mean = sum * (1.0f / cD);
    float vs = 0.f;
#pragma unroll
    for (int j = 0; j < 4; ++j) {
        int d = lane + 64 * j;
        float t = (d < cD) ? (vals[j] - mean) : 0.f;
        vs += t * t;
    }
#pragma unroll
    for (int off = 1; off < 64; off <<= 1) vs += __shfl_xor(vs, off);
    float rstd = rsqrtf(vs * (1.0f / cD) + EPSF);
    float* yr = y + (size_t)row * cD;
    unsigned short* br = ybf + (size_t)row * cKp;
#pragma unroll
    for (int j = 0; j < 4; ++j) {
        int d = lane + 64 * j;
        if (d < cD) {
            float r = (vals[j] - mean) * rstd * g[d] + be[d];
            yr[d] = r;
            br[d] = f2bf(r);
        }
    }
}

// ---------------- final copy ----------------
__global__ __launch_bounds__(256) void copy_out_kernel(
    const float* __restrict__ src, float* __restrict__ out)
{
    int idx = blockIdx.x * 256 + threadIdx.x;
    constexpr int total = cB * (cS - cPAST) * cD;
    if (idx >= total) return;
    int d = idx % cD;
    int r = idx / cD;
    int b = r / (cS - cPAST);
    int i = r % (cS - cPAST);
    out[idx] = src[((size_t)b * cS + cPAST + i) * cD + d];
}

extern "C" void kernel_launch(void* const* d_in, const int* in_sizes, int n_in,
                              void* d_out, int out_size, void* d_ws, size_t ws_size,
                              hipStream_t stream) {
    (void)in_sizes; (void)n_in; (void)out_size; (void)ws_size;
    const float* hand_t       = (const float*)d_in[0];
    const float* head_t       = (const float*)d_in[1];
    const float* hand_m1      = (const float*)d_in[2];
    const float* head_m1      = (const float*)d_in[3];
    const float* c_hand_t     = (const float*)d_in[4];
    const float* c_head_t     = (const float*)d_in[5];
    const float* c_hand_m1    = (const float*)d_in[6];
    const float* c_head_m1    = (const float*)d_in[7];
    const float* state_t      = (const float*)d_in[8];
    const float* state_m1     = (const float*)d_in[9];
    const float* hand_pose_m1 = (const float*)d_in[10];
    const float* head_pose_m1 = (const float*)d_in[11];
    const float* hand_pose_t  = (const float*)d_in[12];
    const float* head_pose_t  = (const float*)d_in[13];
    const float* Wq = (const float*)d_in[14];
    const float* Wk = (const float*)d_in[15];
    const float* Wv = (const float*)d_in[16];
    const float* Wo = (const float*)d_in[17];
    const float* W1 = (const float*)d_in[18];
    const float* W2 = (const float*)d_in[19];
    const float* bq = (const float*)d_in[20];
    const float* bk = (const float*)d_in[21];
    const float* bv = (const float*)d_in[22];
    const float* bo = (const float*)d_in[23];
    const float* b1 = (const float*)d_in[24];
    const float* b2 = (const float*)d_in[25];
    const float* g1 = (const float*)d_in[26];
    const float* be1 = (const float*)d_in[27];
    const float* g2 = (const float*)d_in[28];
    const float* be2 = (const float*)d_in[29];

    // ---- workspace layout ----
    char* p = (char*)d_ws;
    auto alloc_f = [&](size_t n) { float* r = (float*)p; p += n * sizeof(float); return r; };
    auto alloc_h = [&](size_t n) { unsigned short* r = (unsigned short*)p; p += n * sizeof(unsigned short); return r; };
    float* srcb  = alloc_f((size_t)cBS * cD);
    float* csb   = alloc_f((size_t)cBS * 4);
    float* resid = alloc_f((size_t)cBS * cD);
    float* s2b   = alloc_f((size_t)cBS * cD);
    unsigned short* src_bf  = alloc_h((size_t)cBS * cKp);
    unsigned short* s2_bf   = alloc_h((size_t)cBS * cKp);
    unsigned short* attn_bf = alloc_h((size_t)cBS * cKp);
    unsigned short* ff_bf   = alloc_h((size_t)cBS * cFF);
    // q/k/vT bf16, contiguous for single zero-span
    constexpr size_t qkvN = (size_t)cB * cH * cSP * 32; // 1,114,112 each
    unsigned short* qbf  = alloc_h(qkvN);
    unsigned short* kbf  = alloc_h(qkvN);
    unsigned short* vtbf = alloc_h(qkvN);
    unsigned short* wqkv = alloc_h((size_t)4 * cL * 65536);   // Wq,Wk,Wv,Wo padded
    unsigned short* w1p  = alloc_h((size_t)cL * 1024 * 256);
    unsigned short* w2p  = alloc_h((size_t)cL * 256 * 1024);

    // ---- setup ----
    convert_all<<<(4 * 262144 + 2 * 1048576 + 255) / 256, 256, 0, stream>>>(
        Wq, Wk, Wv, Wo, W1, W2, wqkv, w1p, w2p);
    const int n32 = (int)(3 * qkvN / 2); // u32 count of q/k/vT span
    zero_init<<<(n32 + 255) / 256, 256, 0, stream>>>(
        (unsigned int*)qbf, n32, src_bf, s2_bf, attn_bf);
    embed_kernel<<<(cBS * cD + 255) / 256, 256, 0, stream>>>(
        hand_t, head_t, hand_m1, head_m1, state_t, state_m1,
        hand_pose_m1, head_pose_m1, hand_pose_t, head_pose_t, srcb, src_bf);
    coords_kernel<<<(cBS + 255) / 256, 256, 0, stream>>>(
        c_hand_t, c_head_t, c_hand_m1, c_head_m1, csb);

    const int mTiles = (cBS + 127) / 128; // 33
    for (int l = 0; l < cL; ++l) {
        const unsigned short* wq_l = wqkv + (size_t)(0 * cL + l) * 65536;
        const unsigned short* wk_l = wqkv + (size_t)(1 * cL + l) * 65536;
        const unsigned short* wv_l = wqkv + (size_t)(2 * cL + l) * 65536;
        const unsigned short* wo_l = wqkv + (size_t)(3 * cL + l) * 65536;
        const unsigned short* w1_l = w1p + (size_t)l * 1024 * 256;
        const unsigned short* w2_l = w2p + (size_t)l * 256 * 1024;
        const float* bq_l = bq + (size_t)l * cD;
        const float* bk_l = bk + (size_t)l * cD;
        const float* bv_l = bv + (size_t)l * cD;
        const float* bo_l = bo + (size_t)l * cD;
        const float* b1_l = b1 + (size_t)l * cFF;
        const float* b2_l = b2 + (size_t)l * cD;
        const float* g1_l = g1 + (size_t)l * cD;
        const float* be1_l = be1 + (size_t)l * cD;
        const float* g2_l = g2 + (size_t)l * cD;
        const float* be2_l = be2 + (size_t)l * cD;

        gemm_qkv_rope<<<dim3(4, mTiles, 3), 256, 0, stream>>>(
            src_bf, wq_l, wk_l, wv_l, bq_l, bk_l, bv_l, csb, qbf, kbf, vtbf);
        attn_mfma<<<dim3((cS + 63) / 64, cB * cH), 256, 0, stream>>>(
            qbf, kbf, vtbf, attn_bf);
        gemm_epi<1><<<dim3(4, mTiles), 256, 0, stream>>>(
            attn_bf, wo_l, bo_l, srcb, resid, nullptr, cBS, cD, cKp, 8);
        ln_kernel<<<(cBS + 3) / 4, 256, 0, stream>>>(resid, g1_l, be1_l, s2b, s2_bf);
        gemm_epi<2><<<dim3(16, mTiles), 256, 0, stream>>>(
            s2_bf, w1_l, b1_l, nullptr, nullptr, ff_bf, cBS, cFF, cKp, 8);
        gemm_epi<1><<<dim3(4, mTiles), 256, 0, stream>>>(
            ff_bf, w2_l, b2_l, s2b, resid, nullptr, cBS, cD, cFF, 32);
        ln_kernel<<<(cBS + 3) / 4, 256, 0, stream>>>(resid, g2_l, be2_l, srcb, src_bf);
    }
    copy_out_kernel<<<(cB * (cS - cPAST) * cD + 255) / 256, 256, 0, stream>>>(
        srcb, (float*)d_out);
}

// Round 4
// 454.426 us; speedup vs baseline: 2.6820x; 1.0979x over previous
//
#include <hip/hip_runtime.h>
#include <cmath>

constexpr int cB = 4, cN = 256, cD = 240, cH = 8, cFF = 1024, cL = 4;
constexpr int cHD = 30, cS = 1030, cPAST = 515, cBS = cB * cS; // 4120
constexpr int cKp = 256;   // padded K for D-sized contractions
constexpr int cSP = 1088;  // padded sequence for attention buffers
constexpr float EPSF = 1e-5f;

typedef __bf16 bf16x8 __attribute__((ext_vector_type(8)));
typedef float f32x4 __attribute__((ext_vector_type(4)));

__device__ inline unsigned short f2bf(float f) {
    unsigned int u = __builtin_bit_cast(unsigned int, f);
    unsigned int r = (u + 0x7fffu + ((u >> 16) & 1u)) >> 16;
    return (unsigned short)r;
}

// ---------------- all weights convert + zero-pad, one dispatch ----------------
__global__ __launch_bounds__(256) void convert_all(
    const float* __restrict__ Wq, const float* __restrict__ Wk,
    const float* __restrict__ Wv, const float* __restrict__ Wo,
    const float* __restrict__ W1, const float* __restrict__ W2,
    unsigned short* __restrict__ wqkv, unsigned short* __restrict__ w1p,
    unsigned short* __restrict__ w2p)
{
    int idx = blockIdx.x * 256 + threadIdx.x;
    if (idx < 4 * 262144) {
        int which = idx >> 18;
        const float* W = (which == 0) ? Wq : (which == 1) ? Wk : (which == 2) ? Wv : Wo;
        int rem = idx & 262143;
        int m = rem >> 16;
        int rc = rem & 65535;
        int r = rc >> 8, c = rc & 255;
        float v = (r < 240 && c < 240) ? W[((size_t)m * 240 + r) * 240 + c] : 0.f;
        wqkv[idx] = f2bf(v);
    } else if (idx < 4 * 262144 + 1048576) {
        int rem = idx - 4 * 262144;
        int m = rem >> 18;
        int rc = rem & 262143;
        int r = rc >> 8, c = rc & 255;
        float v = (c < 240) ? W1[((size_t)m * 1024 + r) * 240 + c] : 0.f;
        w1p[rem] = f2bf(v);
    } else if (idx < 4 * 262144 + 2 * 1048576) {
        int rem = idx - 4 * 262144 - 1048576;
        int m = rem >> 18;
        int rc = rem & 262143;
        int r = rc >> 10, c = rc & 1023;
        float v = (r < 240) ? W2[((size_t)m * 240 + r) * 1024 + c] : 0.f;
        w2p[rem] = f2bf(v);
    }
}

// ---------------- zero-init: q/k/vT bf16 span + pad cols of activation bufs ----------------
__global__ __launch_bounds__(256) void zero_init(
    unsigned int* __restrict__ span, int n32,
    unsigned short* __restrict__ a, unsigned short* __restrict__ b,
    unsigned short* __restrict__ c)
{
    int idx = blockIdx.x * 256 + threadIdx.x;
    if (idx < n32) span[idx] = 0u;
    if (idx < cBS * 8) {
        int r = idx >> 3, j = idx & 7;
        ((unsigned int*)(a + (size_t)r * 256 + 240))[j] = 0u;
        ((unsigned int*)(b + (size_t)r * 256 + 240))[j] = 0u;
        ((unsigned int*)(c + (size_t)r * 256 + 240))[j] = 0u;
    }
}

// ---------------- embed: build src (BS x D) f32 + bf16 padded copy ----------------
__global__ __launch_bounds__(256) void embed_kernel(
    const float* __restrict__ hand_t, const float* __restrict__ head_t,
    const float* __restrict__ hand_m1, const float* __restrict__ head_m1,
    const float* __restrict__ state_t, const float* __restrict__ state_m1,
    const float* __restrict__ hand_pose_m1, const float* __restrict__ head_pose_m1,
    const float* __restrict__ hand_pose_t, const float* __restrict__ head_pose_t,
    float* __restrict__ src, unsigned short* __restrict__ sbf)
{
    int idx = blockIdx.x * 256 + threadIdx.x;
    if (idx >= cBS * cD) return;
    int d = idx % cD;
    int r = idx / cD;
    int b = r / cS, s = r % cS;
    const float* p; int off;
    if (s == 0)                  { p = state_m1;     off = b * cD + d; }
    else if (s == 1)             { p = hand_pose_m1; off = b * cD + d; }
    else if (s == 2)             { p = head_pose_m1; off = b * cD + d; }
    else if (s < 3 + cN)         { p = hand_m1;      off = (b * cN + (s - 3)) * cD + d; }
    else if (s < 3 + 2 * cN)     { p = head_m1;      off = (b * cN + (s - 3 - cN)) * cD + d; }
    else if (s == cPAST)         { p = state_t;      off = b * cD + d; }
    else if (s == cPAST + 1)     { p = hand_pose_t;  off = b * cD + d; }
    else if (s == cPAST + 2)     { p = head_pose_t;  off = b * cD + d; }
    else if (s < cPAST + 3 + cN) { p = hand_t;       off = (b * cN + (s - cPAST - 3)) * cD + d; }
    else                         { p = head_t;       off = (b * cN + (s - cPAST - 3 - cN)) * cD + d; }
    float v = p[off];
    src[idx] = v;
    sbf[(size_t)r * cKp + d] = f2bf(v);
}

// ---------------- coords ----------------
__global__ __launch_bounds__(256) void coords_kernel(
    const float* __restrict__ ch_t, const float* __restrict__ cd_t,
    const float* __restrict__ ch_m1, const float* __restrict__ cd_m1,
    float* __restrict__ cs)
{
    int r = blockIdx.x * 256 + threadIdx.x;
    if (r >= cBS) return;
    int b = r / cS, s = r % cS;
    float x = 0.f, y = 0.f, z = 0.f;
    const float* p = nullptr; int i = 0;
    if (s >= 3 && s < 3 + cN)                       { p = ch_m1; i = s - 3; }
    else if (s >= 3 + cN && s < 3 + 2 * cN)         { p = cd_m1; i = s - 3 - cN; }
    else if (s >= cPAST + 3 && s < cPAST + 3 + cN)  { p = ch_t;  i = s - cPAST - 3; }
    else if (s >= cPAST + 3 + cN)                   { p = cd_t;  i = s - cPAST - 3 - cN; }
    if (p) { x = p[(b * cN + i) * 3 + 0]; y = p[(b * cN + i) * 3 + 1]; z = p[(b * cN + i) * 3 + 2]; }
    cs[r * 3 + 0] = x; cs[r * 3 + 1] = y; cs[r * 3 + 2] = z;
}

// ================= MFMA GEMM core (validated round 2) =================
#define GEMM_CORE(A_PTR, W_PTR, M_, KA_, NK_)                                                 \
    __shared__ unsigned short Al[128][40];                                                    \
    __shared__ unsigned short Bl[64][40];                                                     \
    const int tid = threadIdx.x;                                                              \
    const int lane = tid & 63;                                                                \
    const int w = tid >> 6;                                                                   \
    const int wm = w >> 1, wn = w & 1;                                                        \
    const int lrow = lane & 15, kq = lane >> 4;                                               \
    const int rowBase = blockIdx.y * 128;                                                     \
    const int colBase = blockIdx.x * 64;                                                      \
    const int sRow = tid >> 2;                                                                \
    const int sS = tid & 3;                                                                   \
    const int ar0 = min(rowBase + sRow, M_ - 1);                                              \
    const int ar1 = min(rowBase + sRow + 64, M_ - 1);                                         \
    const int wr = colBase + sRow;                                                            \
    const unsigned short* a0p = A_PTR + (size_t)ar0 * KA_ + sS * 8;                           \
    const unsigned short* a1p = A_PTR + (size_t)ar1 * KA_ + sS * 8;                           \
    const unsigned short* wp  = W_PTR + (size_t)wr * KA_ + sS * 8;                            \
    f32x4 acc[4][2] = {};                                                                     \
    int4 ra0 = *(const int4*)a0p;                                                             \
    int4 ra1 = *(const int4*)a1p;                                                             \
    int4 rb  = *(const int4*)wp;                                                              \
    for (int ks = 0; ks < NK_; ++ks) {                                                        \
        __syncthreads();                                                                      \
        *(int4*)&Al[sRow][sS * 8]      = ra0;                                                 \
        *(int4*)&Al[sRow + 64][sS * 8] = ra1;                                                 \
        *(int4*)&Bl[sRow][sS * 8]      = rb;                                                  \
        __syncthreads();                                                                      \
        if (ks + 1 < NK_) {                                                                   \
            int kk = (ks + 1) * 32;                                                           \
            ra0 = *(const int4*)(a0p + kk);                                                   \
            ra1 = *(const int4*)(a1p + kk);                                                   \
            rb  = *(const int4*)(wp + kk);                                                    \
        }                                                                                     \
        bf16x8 af[4], bfr[2];                                                                 \
        _Pragma("unroll")                                                                     \
        for (int i = 0; i < 4; ++i)                                                           \
            af[i] = *(const bf16x8*)&Al[wm * 64 + i * 16 + lrow][kq * 8];                     \
        _Pragma("unroll")                                                                     \
        for (int j = 0; j < 2; ++j)                                                           \
            bfr[j] = *(const bf16x8*)&Bl[wn * 32 + j * 16 + lrow][kq * 8];                    \
        _Pragma("unroll")                                                                     \
        for (int i = 0; i < 4; ++i)                                                           \
            _Pragma("unroll")                                                                 \
            for (int j = 0; j < 2; ++j)                                                       \
                acc[i][j] = __builtin_amdgcn_mfma_f32_16x16x32_bf16(af[i], bfr[j], acc[i][j], 0, 0, 0); \
    }

// EPI: 1 = +bias+residual -> f32 out (ld 240) ; 2 = gelu(+bias) -> bf16 out (ld 1024)
template<int EPI>
__global__ __launch_bounds__(256) void gemm_epi(
    const unsigned short* __restrict__ A, const unsigned short* __restrict__ W,
    const float* __restrict__ bias, const float* __restrict__ Rs,
    float* __restrict__ outF, unsigned short* __restrict__ outB,
    int M, int Nreal, int Ka, int nK)
{
    GEMM_CORE(A, W, M, Ka, nK)
#pragma unroll
    for (int i = 0; i < 4; ++i) {
#pragma unroll
        for (int j = 0; j < 2; ++j) {
            int col = colBase + wn * 32 + j * 16 + lrow;
            if (col >= Nreal) continue;
            float bcol = bias[col];
            f32x4 v = acc[i][j];
#pragma unroll
            for (int r = 0; r < 4; ++r) {
                int row = rowBase + wm * 64 + i * 16 + kq * 4 + r;
                if (row >= M) continue;
                float t = v[r] + bcol;
                if (EPI == 1) {
                    outF[(size_t)row * 240 + col] = t + Rs[(size_t)row * 240 + col];
                } else {
                    float gl = 0.5f * t * (1.0f + erff(t * 0.70710678118654752f));
                    outB[(size_t)row * 1024 + col] = f2bf(gl);
                }
            }
        }
    }
}

// ---------------- QKV GEMM with fused RoPE; writes bf16 q,k (BH,SP,32) and V^T (BH,32,SP) ----
__global__ __launch_bounds__(256) void gemm_qkv_rope(
    const unsigned short* __restrict__ A,
    const unsigned short* __restrict__ Wqp, const unsigned short* __restrict__ Wkp,
    const unsigned short* __restrict__ Wvp,
    const float* __restrict__ bq, const float* __restrict__ bk, const float* __restrict__ bv,
    const float* __restrict__ cs,
    unsigned short* __restrict__ qbf, unsigned short* __restrict__ kbf,
    unsigned short* __restrict__ vtbf)
{
    const int z = blockIdx.z;
    const unsigned short* Wsel = (z == 0) ? Wqp : (z == 1) ? Wkp : Wvp;
    const float* bias = (z == 0) ? bq : (z == 1) ? bk : bv;
    GEMM_CORE(A, Wsel, cBS, cKp, 8)
    if (z == 2) {
        // V^T: rows of a frag are 4 consecutive s -> packed dword stores
#pragma unroll
        for (int i = 0; i < 4; ++i) {
#pragma unroll
            for (int j = 0; j < 2; ++j) {
                int col = colBase + wn * 32 + j * 16 + lrow;
                if (col >= cD) continue;
                float bcol = bias[col];
                int hh = col / cHD, hd = col % cHD;
                f32x4 vv = acc[i][j];
                int row0 = rowBase + wm * 64 + i * 16 + kq * 4;
                int b0 = row0 / cS, s0 = row0 - b0 * cS;
                if (row0 + 3 < cBS && s0 + 3 < cS) {
                    unsigned int lo = (unsigned)f2bf(vv[0] + bcol) | ((unsigned)f2bf(vv[1] + bcol) << 16);
                    unsigned int hi = (unsigned)f2bf(vv[2] + bcol) | ((unsigned)f2bf(vv[3] + bcol) << 16);
                    size_t base = ((size_t)(b0 * cH + hh) * 32 + hd) * cSP + s0;
                    *(unsigned int*)&vtbf[base]     = lo;
                    *(unsigned int*)&vtbf[base + 2] = hi;
                } else {
#pragma unroll
                    for (int r = 0; r < 4; ++r) {
                        int row = row0 + r;
                        if (row >= cBS) continue;
                        int bb = row / cS, ss = row - bb * cS;
                        vtbf[((size_t)(bb * cH + hh) * 32 + hd) * cSP + ss] = f2bf(vv[r] + bcol);
                    }
                }
            }
        }
    } else {
#pragma unroll
        for (int i = 0; i < 4; ++i) {
#pragma unroll
            for (int j = 0; j < 2; ++j) {
                int col = colBase + wn * 32 + j * 16 + lrow;
                bool colok = col < cD;
                int cc = colok ? col : 0;
                float bcol = colok ? bias[cc] : 0.f;
                int hh = cc / cHD, hd = cc % cHD;
                int a3 = hd / 10, jj = (hd % 10) >> 1;
                float invf = __expf(-1.8420680743952367f * (float)jj);
                f32x4 vv = acc[i][j];
#pragma unroll
                for (int r = 0; r < 4; ++r) {
                    int row = rowBase + wm * 64 + i * 16 + kq * 4 + r;
                    bool rowok = row < cBS;
                    int rowc = rowok ? row : 0;
                    float val = vv[r] + bcol;
                    float pval = __shfl_xor(val, 1);   // partner col (pairs are adjacent lanes)
                    int b = rowc / cS, s = rowc - b * cS;
                    size_t bh = (size_t)(b * cH + hh);
                    float ang = cs[rowc * 3 + a3] * invf;
                    float sn, co;
                    __sincosf(ang, &sn, &co);
                    float outv = (hd & 1) ? (pval * sn + val * co) : (val * co - pval * sn);
                    if (colok && rowok) {
                        unsigned short* dst = (z == 0) ? qbf : kbf;
                        dst[(bh * cSP + s) * 32 + hd] = f2bf(outv);
                    }
                }
            }
        }
    }
}

// ------- MFMA flash attention, kv-split x2: 32 q-rows/block, 4 waves = 2 qh x 2 kvh -------
__global__ __launch_bounds__(256) void attn_mfma(
    const unsigned short* __restrict__ qbf, const unsigned short* __restrict__ kbf,
    const unsigned short* __restrict__ vtbf, unsigned short* __restrict__ outb)
{
    __shared__ unsigned short Pl[4][16][72];  // per-wave P staging
    __shared__ float Ol[2][16][32];           // kv-half-1 partial O per q-half
    __shared__ float Ml[2][16];
    __shared__ float Ll[2][16];
    const int tid = threadIdx.x, lane = tid & 63, w = tid >> 6;
    const int qh = w & 1, kvh = w >> 1;
    const int bh = blockIdx.y, b = bh >> 3, h = bh & 7;
    const int qbase = blockIdx.x * 32;
    const int q0 = qbase + qh * 16;
    const int lr = lane & 15, lg = lane >> 4;
    const float scl = 0.18257418583505536f; // 1/sqrt(30)
    const f32x4 czero = {0.f, 0.f, 0.f, 0.f};
    bf16x8 qf = *(const bf16x8*)&qbf[((size_t)bh * cSP + q0 + lr) * 32 + lg * 8];
    float m[4], l[4];
    f32x4 o0 = czero, o1 = czero;
#pragma unroll
    for (int r = 0; r < 4; ++r) { m[r] = -3.0e38f; l[r] = 0.f; }
    // tile range for this block, split between kv-halves
    const int t0 = (qbase >= cPAST) ? 8 : 0;   // all-masked rows start at kb=512
    const int cnt = 17 - t0;
    const int halfA = (cnt + 1) >> 1;
    const int tstart = t0 + (kvh ? halfA : 0);
    const int tend = kvh ? 17 : t0 + halfA;
    const int qrow_b = q0 + lg * 4;
    for (int tt = tstart; tt < tend; ++tt) {
        const int kb = tt * 64;
        f32x4 c[4];
#pragma unroll
        for (int t = 0; t < 4; ++t) {
            bf16x8 kf = *(const bf16x8*)&kbf[((size_t)bh * cSP + kb + 16 * t + lr) * 32 + lg * 8];
            c[t] = __builtin_amdgcn_mfma_f32_16x16x32_bf16(qf, kf, czero, 0, 0, 0);
        }
        // scale + mask (C layout: col=key=lr per subtile, row=lg*4+r)
#pragma unroll
        for (int t = 0; t < 4; ++t) {
            int key = kb + 16 * t + lr;
            bool koob = key >= cS;
            bool kpast = key < cPAST;
#pragma unroll
            for (int r = 0; r < 4; ++r) {
                float s = c[t][r] * scl;
                bool msk = koob || ((qrow_b + r >= cPAST) && kpast);
                c[t][r] = msk ? -3.0e38f : s;
            }
        }
        float mx[4];
#pragma unroll
        for (int r = 0; r < 4; ++r)
            mx[r] = fmaxf(fmaxf(c[0][r], c[1][r]), fmaxf(c[2][r], c[3][r]));
#pragma unroll
        for (int off = 1; off < 16; off <<= 1)
#pragma unroll
            for (int r = 0; r < 4; ++r)
                mx[r] = fmaxf(mx[r], __shfl_xor(mx[r], off));
        float corr[4], me[4], ps[4];
#pragma unroll
        for (int r = 0; r < 4; ++r) {
            float mn = fmaxf(m[r], mx[r]);
            corr[r] = __expf(m[r] - mn);
            m[r] = mn;
            me[r] = fmaxf(mn, -1.0e30f);  // floor: all-masked tile -> P = 0
            ps[r] = 0.f;
        }
#pragma unroll
        for (int t = 0; t < 4; ++t)
#pragma unroll
            for (int r = 0; r < 4; ++r) {
                float p = __expf(c[t][r] - me[r]);
                c[t][r] = p;
                ps[r] += p;
            }
#pragma unroll
        for (int off = 1; off < 16; off <<= 1)
#pragma unroll
            for (int r = 0; r < 4; ++r)
                ps[r] += __shfl_xor(ps[r], off);
#pragma unroll
        for (int r = 0; r < 4; ++r) {
            l[r] = l[r] * corr[r] + ps[r];
            o0[r] *= corr[r];
            o1[r] *= corr[r];
        }
#pragma unroll
        for (int t = 0; t < 4; ++t)
#pragma unroll
            for (int r = 0; r < 4; ++r)
                Pl[w][lg * 4 + r][16 * t + lr] = f2bf(c[t][r]);
#pragma unroll
        for (int c2 = 0; c2 < 2; ++c2) {
            bf16x8 pa  = *(const bf16x8*)&Pl[w][lr][c2 * 32 + lg * 8];
            bf16x8 bv0 = *(const bf16x8*)&vtbf[((size_t)bh * 32 + lr) * cSP + kb + c2 * 32 + lg * 8];
            bf16x8 bv1 = *(const bf16x8*)&vtbf[((size_t)bh * 32 + 16 + lr) * cSP + kb + c2 * 32 + lg * 8];
            o0 = __builtin_amdgcn_mfma_f32_16x16x32_bf16(pa, bv0, o0, 0, 0, 0);
            o1 = __builtin_amdgcn_mfma_f32_16x16x32_bf16(pa, bv1, o1, 0, 0, 0);
        }
    }
    if (kvh == 1) {
#pragma unroll
        for (int r = 0; r < 4; ++r) {
            int row = lg * 4 + r;
            if (lr == 0) { Ml[qh][row] = m[r]; Ll[qh][row] = l[r]; }
            Ol[qh][row][lr]      = o0[r];
            Ol[qh][row][16 + lr] = o1[r];
        }
    }
    __syncthreads();
    if (kvh == 0) {
#pragma unroll
        for (int r = 0; r < 4; ++r) {
            int row = lg * 4 + r;
            float m2 = Ml[qh][row], l2 = Ll[qh][row];
            float mn = fmaxf(m[r], m2);
            float ca = __expf(m[r] - mn);
            float cb = __expf(m2 - mn);
            l[r] = l[r] * ca + l2 * cb;
            o0[r] = o0[r] * ca + Ol[qh][row][lr] * cb;
            o1[r] = o1[r] * ca + Ol[qh][row][16 + lr] * cb;
            int q = qrow_b + r;
            if (q >= cS) continue;
            float inv = 1.0f / l[r];
            unsigned short* op = outb + ((size_t)(b * cS + q)) * cKp + h * cHD;
            op[lr] = f2bf(o0[r] * inv);
            if (lr < 14) op[16 + lr] = f2bf(o1[r] * inv);
        }
    }
}

// ---------------- LayerNorm: one row (240) per wave; writes f32 + padded bf16 ----------------
__global__ __launch_bounds__(256) void ln_kernel(
    const float* __restrict__ x, const float* __restrict__ g,
    const float* __restrict__ be, float* __restrict__ y, unsigned short* __restrict__ ybf)
{
    int row = blockIdx.x * 4 + (threadIdx.x >> 6);
    int lane = threadIdx.x & 63;
    if (row >= cBS) return;
    const float* xr = x + (size_t)row * cD;
    float vals[4];
    float sum = 0.f;
#pragma unroll
    for (int j = 0; j < 4; ++j) {
        int d = lane + 64 * j;
        vals[j] = (d < cD) ? xr[d] : 0.f;
        sum += vals[j];
    }
#pragma unroll
    for (int off = 1; off < 64; off <<= 1) sum += __shfl_xor(sum, off);
    float mean = sum * (1.0f / cD);
    float vs = 0.f;
#pragma unroll
    for (int j = 0; j < 4; ++j) {
        int d = lane + 64 * j;
        float t = (d < cD) ? (vals[j] - mean) : 0.f;
        vs += t * t;
    }
#pragma unroll
    for (int off = 1; off < 64; off <<= 1) vs += __shfl_xor(vs, off);
    float rstd = rsqrtf(vs * (1.0f / cD) + EPSF);
    float* yr = y + (size_t)row * cD;
    unsigned short* br = ybf + (size_t)row * cKp;
#pragma unroll
    for (int j = 0; j < 4; ++j) {
        int d = lane + 64 * j;
        if (d < cD) {
            float r = (vals[j] - mean) * rstd * g[d] + be[d];
            yr[d] = r;
            br[d] = f2bf(r);
        }
    }
}

// ---------------- final-layer LN2: write only rows >= PAST straight into d_out ----------------
__global__ __launch_bounds__(256) void ln_final(
    const float* __restrict__ x, const float* __restrict__ g,
    const float* __restrict__ be, float* __restrict__ out)
{
    int idx = blockIdx.x * 4 + (threadIdx.x >> 6);   // 0 .. 4*515-1
    int lane = threadIdx.x & 63;
    constexpr int NT = cS - cPAST; // 515
    if (idx >= cB * NT) return;
    int b = idx / NT, s = cPAST + idx % NT;
    const float* xr = x + ((size_t)b * cS + s) * cD;
    float vals[4];
    float sum = 0.f;
#pragma unroll
    for (int j = 0; j < 4; ++j) {
        int d = lane + 64 * j;
        vals[j] = (d < cD) ? xr[d] : 0.f;
        sum += vals[j];
    }
#pragma unroll
    for (int off = 1; off < 64; off <<= 1) sum += __shfl_xor(sum, off);
    float mean = sum * (1.0f / cD);
    float vs = 0.f;
#pragma unroll
    for (int j = 0; j < 4; ++j) {
        int d = lane + 64 * j;
        float t = (d < cD) ? (vals[j] - mean) : 0.f;
        vs += t * t;
    }
#pragma unroll
    for (int off = 1; off < 64; off <<= 1) vs += __shfl_xor(vs, off);
    float rstd = rsqrtf(vs * (1.0f / cD) + EPSF);
    float* yr = out + (size_t)idx * cD;
#pragma unroll
    for (int j = 0; j < 4; ++j) {
        int d = lane + 64 * j;
        if (d < cD) yr[d] = (vals[j] - mean) * rstd * g[d] + be[d];
    }
}

extern "C" void kernel_launch(void* const* d_in, const int* in_sizes, int n_in,
                              void* d_out, int out_size, void* d_ws, size_t ws_size,
                              hipStream_t stream) {
    (void)in_sizes; (void)n_in; (void)out_size; (void)ws_size;
    const float* hand_t       = (const float*)d_in[0];
    const float* head_t       = (const float*)d_in[1];
    const float* hand_m1      = (const float*)d_in[2];
    const float* head_m1      = (const float*)d_in[3];
    const float* c_hand_t     = (const float*)d_in[4];
    const float* c_head_t     = (const float*)d_in[5];
    const float* c_hand_m1    = (const float*)d_in[6];
    const float* c_head_m1    = (const float*)d_in[7];
    const float* state_t      = (const float*)d_in[8];
    const float* state_m1     = (const float*)d_in[9];
    const float* hand_pose_m1 = (const float*)d_in[10];
    const float* head_pose_m1 = (const float*)d_in[11];
    const float* hand_pose_t  = (const float*)d_in[12];
    const float* head_pose_t  = (const float*)d_in[13];
    const float* Wq = (const float*)d_in[14];
    const float* Wk = (const float*)d_in[15];
    const float* Wv = (const float*)d_in[16];
    const float* Wo = (const float*)d_in[17];
    const float* W1 = (const float*)d_in[18];
    const float* W2 = (const float*)d_in[19];
    const float* bq = (const float*)d_in[20];
    const float* bk = (const float*)d_in[21];
    const float* bv = (const float*)d_in[22];
    const float* bo = (const float*)d_in[23];
    const float* b1 = (const float*)d_in[24];
    const float* b2 = (const float*)d_in[25];
    const float* g1 = (const float*)d_in[26];
    const float* be1 = (const float*)d_in[27];
    const float* g2 = (const float*)d_in[28];
    const float* be2 = (const float*)d_in[29];

    // ---- workspace layout ----
    char* p = (char*)d_ws;
    auto alloc_f = [&](size_t n) { float* r = (float*)p; p += n * sizeof(float); return r; };
    auto alloc_h = [&](size_t n) { unsigned short* r = (unsigned short*)p; p += n * sizeof(unsigned short); return r; };
    float* srcb  = alloc_f((size_t)cBS * cD);
    float* csb   = alloc_f((size_t)cBS * 4);
    float* resid = alloc_f((size_t)cBS * cD);
    float* s2b   = alloc_f((size_t)cBS * cD);
    unsigned short* src_bf  = alloc_h((size_t)cBS * cKp);
    unsigned short* s2_bf   = alloc_h((size_t)cBS * cKp);
    unsigned short* attn_bf = alloc_h((size_t)cBS * cKp);
    unsigned short* ff_bf   = alloc_h((size_t)cBS * cFF);
    constexpr size_t qkvN = (size_t)cB * cH * cSP * 32;
    unsigned short* qbf  = alloc_h(qkvN);
    unsigned short* kbf  = alloc_h(qkvN);
    unsigned short* vtbf = alloc_h(qkvN);
    unsigned short* wqkv = alloc_h((size_t)4 * cL * 65536);
    unsigned short* w1p  = alloc_h((size_t)cL * 1024 * 256);
    unsigned short* w2p  = alloc_h((size_t)cL * 256 * 1024);

    // ---- setup ----
    convert_all<<<(4 * 262144 + 2 * 1048576 + 255) / 256, 256, 0, stream>>>(
        Wq, Wk, Wv, Wo, W1, W2, wqkv, w1p, w2p);
    const int n32 = (int)(3 * qkvN / 2);
    zero_init<<<(n32 + 255) / 256, 256, 0, stream>>>(
        (unsigned int*)qbf, n32, src_bf, s2_bf, attn_bf);
    embed_kernel<<<(cBS * cD + 255) / 256, 256, 0, stream>>>(
        hand_t, head_t, hand_m1, head_m1, state_t, state_m1,
        hand_pose_m1, head_pose_m1, hand_pose_t, head_pose_t, srcb, src_bf);
    coords_kernel<<<(cBS + 255) / 256, 256, 0, stream>>>(
        c_hand_t, c_head_t, c_hand_m1, c_head_m1, csb);

    const int mTiles = (cBS + 127) / 128; // 33
    for (int l = 0; l < cL; ++l) {
        const unsigned short* wq_l = wqkv + (size_t)(0 * cL + l) * 65536;
        const unsigned short* wk_l = wqkv + (size_t)(1 * cL + l) * 65536;
        const unsigned short* wv_l = wqkv + (size_t)(2 * cL + l) * 65536;
        const unsigned short* wo_l = wqkv + (size_t)(3 * cL + l) * 65536;
        const unsigned short* w1_l = w1p + (size_t)l * 1024 * 256;
        const unsigned short* w2_l = w2p + (size_t)l * 256 * 1024;
        const float* bq_l = bq + (size_t)l * cD;
        const float* bk_l = bk + (size_t)l * cD;
        const float* bv_l = bv + (size_t)l * cD;
        const float* bo_l = bo + (size_t)l * cD;
        const float* b1_l = b1 + (size_t)l * cFF;
        const float* b2_l = b2 + (size_t)l * cD;
        const float* g1_l = g1 + (size_t)l * cD;
        const float* be1_l = be1 + (size_t)l * cD;
        const float* g2_l = g2 + (size_t)l * cD;
        const float* be2_l = be2 + (size_t)l * cD;

        gemm_qkv_rope<<<dim3(4, mTiles, 3), 256, 0, stream>>>(
            src_bf, wq_l, wk_l, wv_l, bq_l, bk_l, bv_l, csb, qbf, kbf, vtbf);
        attn_mfma<<<dim3((cS + 31) / 32, cB * cH), 256, 0, stream>>>(
            qbf, kbf, vtbf, attn_bf);
        gemm_epi<1><<<dim3(4, mTiles), 256, 0, stream>>>(
            attn_bf, wo_l, bo_l, srcb, resid, nullptr, cBS, cD, cKp, 8);
        ln_kernel<<<(cBS + 3) / 4, 256, 0, stream>>>(resid, g1_l, be1_l, s2b, s2_bf);
        gemm_epi<2><<<dim3(16, mTiles), 256, 0, stream>>>(
            s2_bf, w1_l, b1_l, nullptr, nullptr, ff_bf, cBS, cFF, cKp, 8);
        gemm_epi<1><<<dim3(4, mTiles), 256, 0, stream>>>(
            ff_bf, w2_l, b2_l, s2b, resid, nullptr, cBS, cD, cFF, 32);
        if (l < cL - 1) {
            ln_kernel<<<(cBS + 3) / 4, 256, 0, stream>>>(resid, g2_l, be2_l, srcb, src_bf);
        } else {
            ln_final<<<(cB * (cS - cPAST) + 3) / 4, 256, 0, stream>>>(
                resid, g2_l, be2_l, (float*)d_out);
        }
    }
}